// Round 7
// baseline (400.927 us; speedup 1.0000x reference)
//
#include <hip/hip_runtime.h>

// GraphConv 3-layer GCN: N=100000 nodes, E=1280000 edges; dims 128->64->64->40.
constexpr int NN = 100000;
constexpr int NE = 1280000;
constexpr int NP = 100352;       // padded N (= 98 * 1024)
constexpr int NBLK = NP / 1024;  // 98 scan chunks

// LDS-segmented histogram geometry.
// 64 KB LDS/block + 1024-thread blocks -> 2 blocks/CU = 32 waves/CU (full).
constexpr int SEGSZ = 16384;                  // 64 KB of int bins per block
constexpr int NSEG = 7;                       // 7*16384 = 114688 >= NN
constexpr int NCHUNK = 64;                    // edge chunks
constexpr int CHSZ = NE / NCHUNK;             // 20000 (exact)

// ---------------------------------------------------------------------------
// Histogram of vals[] (node ids) into partial[c][n] (stride NN), via LDS bins.
// ---------------------------------------------------------------------------
__global__ __launch_bounds__(1024) void hist_lds_kernel(
    const int* __restrict__ vals, int* __restrict__ partial) {
  __shared__ int hcnt[SEGSZ];
  const int s = blockIdx.x % NSEG, c = blockIdx.x / NSEG;
  const int t = threadIdx.x;
#pragma unroll 4
  for (int i = t; i < SEGSZ; i += 1024) hcnt[i] = 0;
  __syncthreads();
  const int lo = s * SEGSZ;
  const int beg = c * CHSZ;
  for (int e = beg + t; e < beg + CHSZ; e += 1024) {
    unsigned v = (unsigned)(vals[e] - lo);
    if (v < (unsigned)SEGSZ) atomicAdd(&hcnt[v], 1);  // LDS atomic
  }
  __syncthreads();
  int* p = partial + (size_t)c * NN;
#pragma unroll 4
  for (int i = t; i < SEGSZ; i += 1024) {
    int n = lo + i;
    if (n < NN) p[n] = hcnt[i];
  }
}

// ---------------------------------------------------------------------------
// Merge chunk-partials per node: cnt_in = sum, pin <- exclusive chunk prefix
// (in place, consumed by fill), norms from both degree sums.
// ---------------------------------------------------------------------------
__global__ __launch_bounds__(256) void merge_kernel(
    int* __restrict__ pin, const int* __restrict__ pout,
    int* __restrict__ cnt_in, float* __restrict__ norm_out,
    float* __restrict__ norm_in) {
  int n = blockIdx.x * 256 + threadIdx.x;
  if (n >= NN) return;
  int run = 0;
#pragma unroll 8
  for (int c = 0; c < NCHUNK; ++c) {
    size_t idx = (size_t)c * NN + n;
    int v = pin[idx];
    pin[idx] = run;
    run += v;
  }
  cnt_in[n] = run;
  int s = 0;
#pragma unroll 8
  for (int c = 0; c < NCHUNK; ++c) s += pout[(size_t)c * NN + n];
  norm_in[n]  = rsqrtf(fmaxf((float)run, 1.0f));
  norm_out[n] = rsqrtf(fmaxf((float)s, 1.0f));
}

// ---------------------------------------------------------------------------
// Two-level exclusive scan of cnt_in -> row_ptr
// ---------------------------------------------------------------------------
__global__ __launch_bounds__(256) void chunk_sum_kernel(
    const int* __restrict__ cnt, int* __restrict__ partial) {
  int t = threadIdx.x;
  int base = blockIdx.x * 1024 + t * 4;
  int s = 0;
#pragma unroll
  for (int j = 0; j < 4; ++j) {
    int gi = base + j;
    s += (gi < NN) ? cnt[gi] : 0;
  }
  __shared__ int r[256];
  r[t] = s;
  __syncthreads();
  for (int off = 128; off > 0; off >>= 1) {
    if (t < off) r[t] += r[t + off];
    __syncthreads();
  }
  if (t == 0) partial[blockIdx.x] = r[0];
}

__global__ __launch_bounds__(128) void partial_scan_kernel(int* __restrict__ partial) {
  int t = threadIdx.x;
  int v = (t < NBLK) ? partial[t] : 0;
  __shared__ int s[128];
  s[t] = v;
  __syncthreads();
  for (int off = 1; off < 128; off <<= 1) {
    int add = (t >= off) ? s[t - off] : 0;
    __syncthreads();
    s[t] += add;
    __syncthreads();
  }
  if (t < NBLK) partial[t] = s[t] - v;  // exclusive
}

__global__ __launch_bounds__(256) void chunk_scan_kernel(
    const int* __restrict__ cnt, const int* __restrict__ partial,
    int* __restrict__ row_ptr) {
  int t = threadIdx.x;
  int base = blockIdx.x * 1024 + t * 4;
  int c[4];
#pragma unroll
  for (int j = 0; j < 4; ++j) {
    int gi = base + j;
    c[j] = (gi < NN) ? cnt[gi] : 0;
  }
  int tsum = c[0] + c[1] + c[2] + c[3];
  __shared__ int s[256];
  s[t] = tsum;
  __syncthreads();
  for (int off = 1; off < 256; off <<= 1) {
    int add = (t >= off) ? s[t - off] : 0;
    __syncthreads();
    s[t] += add;
    __syncthreads();
  }
  int run = s[t] - tsum + partial[blockIdx.x];
#pragma unroll
  for (int j = 0; j < 4; ++j) {
    int gi = base + j;
    if (gi <= NN) row_ptr[gi] = run;
    run += c[j];
  }
}

// ---------------------------------------------------------------------------
// CSR fill via LDS cursors (no device atomics).
// ---------------------------------------------------------------------------
__global__ __launch_bounds__(1024) void fill_lds_kernel(
    const int* __restrict__ src, const int* __restrict__ dst,
    const int* __restrict__ row_ptr, const int* __restrict__ pin,
    int* __restrict__ csr_src) {
  __shared__ int cur[SEGSZ];
  const int s = blockIdx.x % NSEG, c = blockIdx.x / NSEG;
  const int t = threadIdx.x;
  const int lo = s * SEGSZ;
  const int* base = pin + (size_t)c * NN;
#pragma unroll 4
  for (int i = t; i < SEGSZ; i += 1024) {
    int n = lo + i;
    cur[i] = (n < NN) ? (row_ptr[n] + base[n]) : 0;
  }
  __syncthreads();
  const int beg = c * CHSZ;
  for (int e = beg + t; e < beg + CHSZ; e += 1024) {
    unsigned d = (unsigned)(dst[e] - lo);
    if (d < (unsigned)SEGSZ) {
      int pos = atomicAdd(&cur[d], 1);  // LDS atomic
      csr_src[pos] = src[e];
    }
  }
}

// ---------------------------------------------------------------------------
// GEMM:  out[row, :] = PRE(in[row, :]) @ W   (PRE = *norm_out when SCALE)
// 64 rows x 64 cols tile, 4x4 micro-tile (400K threads -> 24+ waves/CU
// possible). W staged PER 32-K CHUNK (8 KB) so total LDS = 16.6 KB
// (round-5's 41.5 KB capped occupancy at 3 blocks/CU). launch_bounds(256,8)
// pushes the allocator to <=64 VGPR for the 8-waves/SIMD occupancy step.
// ---------------------------------------------------------------------------
template <int K, int COLS, bool SCALE>
__global__ __launch_bounds__(256, 8) void gemm_kernel(
    const float* __restrict__ in, const float* __restrict__ W,
    const float* __restrict__ norm_out, float* __restrict__ out) {
  constexpr int KC = 32;
  constexpr int XS = 68;  // 64 rows + pad; 68*4B = 272B, 16B-aligned rows
  __shared__ float Wl[KC][64];
  __shared__ float xt[KC][XS];

  const int tid = threadIdx.x;
  const int tc = tid & 15;   // col group: cols 4*tc .. 4*tc+3
  const int tr = tid >> 4;   // row group: rows 4*tr .. 4*tr+3
  const int row0 = blockIdx.x * 64;

  float acc[4][4] = {};

  for (int kc = 0; kc < K; kc += KC) {
    // Stage this chunk of W (8 KB, coalesced, L2-hot; zero-pad cols >= COLS)
    for (int i = tid; i < KC * 64; i += 256) {
      int k = i >> 6, c = i & 63;
      Wl[k][c] = (c < COLS) ? W[(kc + k) * COLS + c] : 0.0f;
    }
    // Stage 64 rows x 32 ks of x, transposed: xt[k][row]
#pragma unroll
    for (int i = 0; i < 8; ++i) {
      int elem = i * 256 + tid;
      int r = elem >> 5;
      int kk = elem & 31;
      int grow = row0 + r;
      float v = 0.0f;
      if (grow < NN) {
        v = in[(size_t)grow * K + kc + kk];
        if constexpr (SCALE) v *= norm_out[grow];
      }
      xt[kk][r] = v;
    }
    __syncthreads();
#pragma unroll
    for (int kk = 0; kk < KC; ++kk) {
      float4 xv = *(const float4*)&xt[kk][4 * tr];
      float4 wv = *(const float4*)&Wl[kk][4 * tc];
      float xa[4] = {xv.x, xv.y, xv.z, xv.w};
      float wa[4] = {wv.x, wv.y, wv.z, wv.w};
#pragma unroll
      for (int r = 0; r < 4; ++r)
#pragma unroll
        for (int c = 0; c < 4; ++c)
          acc[r][c] = fmaf(xa[r], wa[c], acc[r][c]);
    }
    __syncthreads();
  }

#pragma unroll
  for (int r = 0; r < 4; ++r) {
    int grow = row0 + 4 * tr + r;
    if (grow < NN) {
#pragma unroll
      for (int c = 0; c < 4; ++c) {
        int col = 4 * tc + c;
        if (col < COLS) out[(size_t)grow * COLS + col] = acc[r][c];
      }
    }
  }
}

// ---------------------------------------------------------------------------
// CSR gather, one wave per node, float4 lanes x 4-edge groups.
// Near the L2-system structural bound (~6.5 distinct-XCD re-reads of m).
// ---------------------------------------------------------------------------
template <int C, bool RELU>
__global__ __launch_bounds__(256) void gather_kernel(
    const float* __restrict__ m, const int* __restrict__ row_ptr,
    const int* __restrict__ csr_src, const float* __restrict__ norm_in,
    const float* __restrict__ norm_out, const float* __restrict__ bias,
    float* __restrict__ outp) {
  constexpr int CV = C / 4;  // float4s per row: 16 (C=64), 10 (C=40)
  const int node = blockIdx.x * 4 + (threadIdx.x >> 6);
  const int lane = threadIdx.x & 63;
  if (node >= NN) return;
  const int beg = row_ptr[node];
  const int end = row_ptr[node + 1];
  const int eg = lane >> 4;
  const int fl = lane & 15;
  const float4* m4 = (const float4*)m;

  float4 acc = {0.f, 0.f, 0.f, 0.f};
#pragma unroll 4
  for (int i = beg + eg; i < end; i += 4) {
    int s = csr_src[i];
    if (fl < CV) {
      float4 v = m4[(size_t)s * CV + fl];
      acc.x += v.x; acc.y += v.y; acc.z += v.z; acc.w += v.w;
    }
  }
  acc.x += __shfl_xor(acc.x, 16); acc.y += __shfl_xor(acc.y, 16);
  acc.z += __shfl_xor(acc.z, 16); acc.w += __shfl_xor(acc.w, 16);
  acc.x += __shfl_xor(acc.x, 32); acc.y += __shfl_xor(acc.y, 32);
  acc.z += __shfl_xor(acc.z, 32); acc.w += __shfl_xor(acc.w, 32);

  if (eg == 0 && fl < CV) {
    float ni = norm_in[node];
    float4 b4 = ((const float4*)bias)[fl];
    float4 r;
    r.x = fmaf(acc.x, ni, b4.x);
    r.y = fmaf(acc.y, ni, b4.y);
    r.z = fmaf(acc.z, ni, b4.z);
    r.w = fmaf(acc.w, ni, b4.w);
    if constexpr (RELU) {
      float no = norm_out[node];
      r.x = fmaxf(r.x, 0.f) * no;
      r.y = fmaxf(r.y, 0.f) * no;
      r.z = fmaxf(r.z, 0.f) * no;
      r.w = fmaxf(r.w, 0.f) * no;
    }
    ((float4*)outp)[(size_t)node * CV + fl] = r;
  }
}

// ---------------------------------------------------------------------------
extern "C" void kernel_launch(void* const* d_in, const int* in_sizes, int n_in,
                              void* d_out, int out_size, void* d_ws, size_t ws_size,
                              hipStream_t stream) {
  const float* x    = (const float*)d_in[0];
  const float* W0   = (const float*)d_in[1];
  const float* b0   = (const float*)d_in[2];
  const float* W1   = (const float*)d_in[3];
  const float* b1   = (const float*)d_in[4];
  const float* W2   = (const float*)d_in[5];
  const float* b2   = (const float*)d_in[6];
  const int*   esrc = (const int*)d_in[7];
  const int*   edst = (const int*)d_in[8];
  float* out = (float*)d_out;

  // Workspace (4B units): norms/row_ptr/cnt_in/partial + csr_src[NE] +
  // m[NN*64] + h[NN*64]. CSR-build transients alias m/h (dead until gemm0):
  // pin = m (NCHUNK*NN = 25.6 MB exactly), pout = h.
  float* f        = (float*)d_ws;
  float* norm_out = f;
  float* norm_in  = f + NP;
  int*   row_ptr  = (int*)(f + 2 * NP);
  int*   cnt_in   = row_ptr + NP;
  int*   partial  = cnt_in + NP;
  int*   csr_src  = partial + 128;
  float* m        = (float*)(csr_src + NE);
  float* h        = m + NN * 64;
  int*   pin      = (int*)m;
  int*   pout     = (int*)h;

  // --- CSR build (dst-sorted) + norms: zero global atomics ---
  hist_lds_kernel<<<NSEG * NCHUNK, 1024, 0, stream>>>(edst, pin);
  hist_lds_kernel<<<NSEG * NCHUNK, 1024, 0, stream>>>(esrc, pout);
  merge_kernel<<<(NN + 255) / 256, 256, 0, stream>>>(pin, pout, cnt_in, norm_out, norm_in);
  chunk_sum_kernel<<<NBLK, 256, 0, stream>>>(cnt_in, partial);
  partial_scan_kernel<<<1, 128, 0, stream>>>(partial);
  chunk_scan_kernel<<<NBLK, 256, 0, stream>>>(cnt_in, partial, row_ptr);
  fill_lds_kernel<<<NSEG * NCHUNK, 1024, 0, stream>>>(esrc, edst, row_ptr, pin, csr_src);

  const int gb = (NN + 63) / 64;
  const int gg = (NN + 3) / 4;

  // Layer 0: m = (x*norm_out) @ W0 ; h = relu(agg*norm_in + b0)*norm_out
  gemm_kernel<128, 64, true><<<gb, 256, 0, stream>>>(x, W0, norm_out, m);
  gather_kernel<64, true><<<gg, 256, 0, stream>>>(m, row_ptr, csr_src, norm_in, norm_out, b0, h);

  // Layer 1: m = h @ W1 ; h = relu(agg*norm_in + b1)*norm_out
  gemm_kernel<64, 64, false><<<gb, 256, 0, stream>>>(h, W1, nullptr, m);
  gather_kernel<64, true><<<gg, 256, 0, stream>>>(m, row_ptr, csr_src, norm_in, norm_out, b1, h);

  // Layer 2: m = h @ W2 (40 cols) ; out = agg*norm_in + b2
  gemm_kernel<64, 40, false><<<gb, 256, 0, stream>>>(h, W2, nullptr, m);
  gather_kernel<40, false><<<gg, 256, 0, stream>>>(m, row_ptr, csr_src, norm_in, norm_out, b2, out);
}

// Round 8
// 315.766 us; speedup vs baseline: 1.2697x; 1.2697x over previous
//
#include <hip/hip_runtime.h>

// GraphConv 3-layer GCN: N=100000 nodes, E=1280000 edges; dims 128->64->64->40.
constexpr int NN = 100000;
constexpr int NE = 1280000;
constexpr int NP = 100352;       // padded N (= 98 * 1024)
constexpr int NBLK = NP / 1024;  // 98 scan chunks

// LDS-segmented histogram geometry.
// 64 KB LDS/block + 1024-thread blocks -> 2 blocks/CU = 32 waves/CU (full).
constexpr int SEGSZ = 16384;                  // 64 KB of int bins per block
constexpr int NSEG = 7;                       // 7*16384 = 114688 >= NN
constexpr int NCHUNK = 64;                    // edge chunks
constexpr int CHSZ = NE / NCHUNK;             // 20000 (exact)

// ---------------------------------------------------------------------------
// Histogram of vals[] (node ids) into partial[c][n] (stride NN), via LDS bins.
// ---------------------------------------------------------------------------
__global__ __launch_bounds__(1024) void hist_lds_kernel(
    const int* __restrict__ vals, int* __restrict__ partial) {
  __shared__ int hcnt[SEGSZ];
  const int s = blockIdx.x % NSEG, c = blockIdx.x / NSEG;
  const int t = threadIdx.x;
#pragma unroll 4
  for (int i = t; i < SEGSZ; i += 1024) hcnt[i] = 0;
  __syncthreads();
  const int lo = s * SEGSZ;
  const int beg = c * CHSZ;
  for (int e = beg + t; e < beg + CHSZ; e += 1024) {
    unsigned v = (unsigned)(vals[e] - lo);
    if (v < (unsigned)SEGSZ) atomicAdd(&hcnt[v], 1);  // LDS atomic
  }
  __syncthreads();
  int* p = partial + (size_t)c * NN;
#pragma unroll 4
  for (int i = t; i < SEGSZ; i += 1024) {
    int n = lo + i;
    if (n < NN) p[n] = hcnt[i];
  }
}

// ---------------------------------------------------------------------------
// Merge chunk-partials per node: cnt_in = sum, pin <- exclusive chunk prefix
// (in place, consumed by fill), norms from both degree sums.
// ---------------------------------------------------------------------------
__global__ __launch_bounds__(256) void merge_kernel(
    int* __restrict__ pin, const int* __restrict__ pout,
    int* __restrict__ cnt_in, float* __restrict__ norm_out,
    float* __restrict__ norm_in) {
  int n = blockIdx.x * 256 + threadIdx.x;
  if (n >= NN) return;
  int run = 0;
#pragma unroll 8
  for (int c = 0; c < NCHUNK; ++c) {
    size_t idx = (size_t)c * NN + n;
    int v = pin[idx];
    pin[idx] = run;
    run += v;
  }
  cnt_in[n] = run;
  int s = 0;
#pragma unroll 8
  for (int c = 0; c < NCHUNK; ++c) s += pout[(size_t)c * NN + n];
  norm_in[n]  = rsqrtf(fmaxf((float)run, 1.0f));
  norm_out[n] = rsqrtf(fmaxf((float)s, 1.0f));
}

// ---------------------------------------------------------------------------
// Two-level exclusive scan of cnt_in -> row_ptr
// ---------------------------------------------------------------------------
__global__ __launch_bounds__(256) void chunk_sum_kernel(
    const int* __restrict__ cnt, int* __restrict__ partial) {
  int t = threadIdx.x;
  int base = blockIdx.x * 1024 + t * 4;
  int s = 0;
#pragma unroll
  for (int j = 0; j < 4; ++j) {
    int gi = base + j;
    s += (gi < NN) ? cnt[gi] : 0;
  }
  __shared__ int r[256];
  r[t] = s;
  __syncthreads();
  for (int off = 128; off > 0; off >>= 1) {
    if (t < off) r[t] += r[t + off];
    __syncthreads();
  }
  if (t == 0) partial[blockIdx.x] = r[0];
}

__global__ __launch_bounds__(128) void partial_scan_kernel(int* __restrict__ partial) {
  int t = threadIdx.x;
  int v = (t < NBLK) ? partial[t] : 0;
  __shared__ int s[128];
  s[t] = v;
  __syncthreads();
  for (int off = 1; off < 128; off <<= 1) {
    int add = (t >= off) ? s[t - off] : 0;
    __syncthreads();
    s[t] += add;
    __syncthreads();
  }
  if (t < NBLK) partial[t] = s[t] - v;  // exclusive
}

__global__ __launch_bounds__(256) void chunk_scan_kernel(
    const int* __restrict__ cnt, const int* __restrict__ partial,
    int* __restrict__ row_ptr) {
  int t = threadIdx.x;
  int base = blockIdx.x * 1024 + t * 4;
  int c[4];
#pragma unroll
  for (int j = 0; j < 4; ++j) {
    int gi = base + j;
    c[j] = (gi < NN) ? cnt[gi] : 0;
  }
  int tsum = c[0] + c[1] + c[2] + c[3];
  __shared__ int s[256];
  s[t] = tsum;
  __syncthreads();
  for (int off = 1; off < 256; off <<= 1) {
    int add = (t >= off) ? s[t - off] : 0;
    __syncthreads();
    s[t] += add;
    __syncthreads();
  }
  int run = s[t] - tsum + partial[blockIdx.x];
#pragma unroll
  for (int j = 0; j < 4; ++j) {
    int gi = base + j;
    if (gi <= NN) row_ptr[gi] = run;
    run += c[j];
  }
}

// ---------------------------------------------------------------------------
// CSR fill via LDS cursors (no device atomics).
// ---------------------------------------------------------------------------
__global__ __launch_bounds__(1024) void fill_lds_kernel(
    const int* __restrict__ src, const int* __restrict__ dst,
    const int* __restrict__ row_ptr, const int* __restrict__ pin,
    int* __restrict__ csr_src) {
  __shared__ int cur[SEGSZ];
  const int s = blockIdx.x % NSEG, c = blockIdx.x / NSEG;
  const int t = threadIdx.x;
  const int lo = s * SEGSZ;
  const int* base = pin + (size_t)c * NN;
#pragma unroll 4
  for (int i = t; i < SEGSZ; i += 1024) {
    int n = lo + i;
    cur[i] = (n < NN) ? (row_ptr[n] + base[n]) : 0;
  }
  __syncthreads();
  const int beg = c * CHSZ;
  for (int e = beg + t; e < beg + CHSZ; e += 1024) {
    unsigned d = (unsigned)(dst[e] - lo);
    if (d < (unsigned)SEGSZ) {
      int pos = atomicAdd(&cur[d], 1);  // LDS atomic
      csr_src[pos] = src[e];
    }
  }
}

// ---------------------------------------------------------------------------
// GEMM:  out[row, :] = PRE(in[row, :]) @ W   (PRE = *norm_out when SCALE)
// 64x64 tile, 4x4 micro-tile (400K threads). W staged per-32-K chunk ->
// LDS 16.6 KB (not occupancy-binding). launch_bounds(256,4): 128-VGPR
// budget -- round 7's (256,8) forced 32 VGPR and SPILLED (157 MB scratch
// fetch/dispatch). float4 staging loads + float4 epilogue stores.
// ---------------------------------------------------------------------------
template <int K, int COLS, bool SCALE>
__global__ __launch_bounds__(256, 4) void gemm_kernel(
    const float* __restrict__ in, const float* __restrict__ W,
    const float* __restrict__ norm_out, float* __restrict__ out) {
  constexpr int KC = 32;
  constexpr int XS = 68;  // 64 rows + pad; 68*4B = 272B, 16B-aligned rows
  __shared__ float Wl[KC][64];
  __shared__ float xt[KC][XS];

  const int tid = threadIdx.x;
  const int tc = tid & 15;   // col group: cols 4*tc .. 4*tc+3
  const int tr = tid >> 4;   // row group: rows 4*tr .. 4*tr+3
  const int row0 = blockIdx.x * 64;

  // Zero-pad Wl cols >= COLS once (visible after first in-loop barrier)
  if constexpr (COLS < 64) {
    for (int i = tid; i < KC * 64; i += 256) {
      int k = i >> 6, c = i & 63;
      if (c >= COLS) Wl[k][c] = 0.0f;
    }
  }

  float acc[4][4] = {};

  for (int kc = 0; kc < K; kc += KC) {
    // Stage W chunk via float4 (rows are 4-float-aligned for COLS=64/40)
    constexpr int CV = COLS / 4;       // 16 or 10
    constexpr int WV = KC * CV;        // 512 or 320
    for (int i = tid; i < WV; i += 256) {
      int k = i / CV, c4 = i - k * CV;
      float4 wv = *(const float4*)&W[(size_t)(kc + k) * COLS + 4 * c4];
      *(float4*)&Wl[k][4 * c4] = wv;
    }
    // Stage x chunk transposed via float4 loads: q = i*256+tid,
    // r = q>>3 (row), k4 = q&7 (float4 within 32-k chunk).
    // Transpose writes: banks (16*k4 + 4j + r) % 32 -> 2 lanes/bank (free).
#pragma unroll
    for (int i = 0; i < 2; ++i) {
      int q = i * 256 + tid;
      int r = q >> 3;
      int k4 = q & 7;
      int grow = row0 + r;
      float4 v = {0.f, 0.f, 0.f, 0.f};
      if (grow < NN) {
        v = *(const float4*)&in[(size_t)grow * K + kc + 4 * k4];
        if constexpr (SCALE) {
          float no = norm_out[grow];
          v.x *= no; v.y *= no; v.z *= no; v.w *= no;
        }
      }
      xt[4 * k4 + 0][r] = v.x;
      xt[4 * k4 + 1][r] = v.y;
      xt[4 * k4 + 2][r] = v.z;
      xt[4 * k4 + 3][r] = v.w;
    }
    __syncthreads();
#pragma unroll
    for (int kk = 0; kk < KC; ++kk) {
      float4 xv = *(const float4*)&xt[kk][4 * tr];
      float4 wv = *(const float4*)&Wl[kk][4 * tc];
      float xa[4] = {xv.x, xv.y, xv.z, xv.w};
      float wa[4] = {wv.x, wv.y, wv.z, wv.w};
#pragma unroll
      for (int r = 0; r < 4; ++r)
#pragma unroll
        for (int c = 0; c < 4; ++c)
          acc[r][c] = fmaf(xa[r], wa[c], acc[r][c]);
    }
    __syncthreads();
  }

  // Epilogue: one float4 store per row (16B-aligned: COLS*4 % 16 == 0)
  if (4 * tc < COLS) {
#pragma unroll
    for (int r = 0; r < 4; ++r) {
      int grow = row0 + 4 * tr + r;
      if (grow < NN) {
        float4 s0 = {acc[r][0], acc[r][1], acc[r][2], acc[r][3]};
        *(float4*)&out[(size_t)grow * COLS + 4 * tc] = s0;
      }
    }
  }
}

// ---------------------------------------------------------------------------
// CSR gather, one wave per node, float4 lanes x 4-edge groups.
// ---------------------------------------------------------------------------
template <int C, bool RELU>
__global__ __launch_bounds__(256) void gather_kernel(
    const float* __restrict__ m, const int* __restrict__ row_ptr,
    const int* __restrict__ csr_src, const float* __restrict__ norm_in,
    const float* __restrict__ norm_out, const float* __restrict__ bias,
    float* __restrict__ outp) {
  constexpr int CV = C / 4;  // float4s per row: 16 (C=64), 10 (C=40)
  const int node = blockIdx.x * 4 + (threadIdx.x >> 6);
  const int lane = threadIdx.x & 63;
  if (node >= NN) return;
  const int beg = row_ptr[node];
  const int end = row_ptr[node + 1];
  const int eg = lane >> 4;
  const int fl = lane & 15;
  const float4* m4 = (const float4*)m;

  float4 acc = {0.f, 0.f, 0.f, 0.f};
#pragma unroll 4
  for (int i = beg + eg; i < end; i += 4) {
    int s = csr_src[i];
    if (fl < CV) {
      float4 v = m4[(size_t)s * CV + fl];
      acc.x += v.x; acc.y += v.y; acc.z += v.z; acc.w += v.w;
    }
  }
  acc.x += __shfl_xor(acc.x, 16); acc.y += __shfl_xor(acc.y, 16);
  acc.z += __shfl_xor(acc.z, 16); acc.w += __shfl_xor(acc.w, 16);
  acc.x += __shfl_xor(acc.x, 32); acc.y += __shfl_xor(acc.y, 32);
  acc.z += __shfl_xor(acc.z, 32); acc.w += __shfl_xor(acc.w, 32);

  if (eg == 0 && fl < CV) {
    float ni = norm_in[node];
    float4 b4 = ((const float4*)bias)[fl];
    float4 r;
    r.x = fmaf(acc.x, ni, b4.x);
    r.y = fmaf(acc.y, ni, b4.y);
    r.z = fmaf(acc.z, ni, b4.z);
    r.w = fmaf(acc.w, ni, b4.w);
    if constexpr (RELU) {
      float no = norm_out[node];
      r.x = fmaxf(r.x, 0.f) * no;
      r.y = fmaxf(r.y, 0.f) * no;
      r.z = fmaxf(r.z, 0.f) * no;
      r.w = fmaxf(r.w, 0.f) * no;
    }
    ((float4*)outp)[(size_t)node * CV + fl] = r;
  }
}

// ---------------------------------------------------------------------------
extern "C" void kernel_launch(void* const* d_in, const int* in_sizes, int n_in,
                              void* d_out, int out_size, void* d_ws, size_t ws_size,
                              hipStream_t stream) {
  const float* x    = (const float*)d_in[0];
  const float* W0   = (const float*)d_in[1];
  const float* b0   = (const float*)d_in[2];
  const float* W1   = (const float*)d_in[3];
  const float* b1   = (const float*)d_in[4];
  const float* W2   = (const float*)d_in[5];
  const float* b2   = (const float*)d_in[6];
  const int*   esrc = (const int*)d_in[7];
  const int*   edst = (const int*)d_in[8];
  float* out = (float*)d_out;

  // Workspace (4B units): norms/row_ptr/cnt_in/partial + csr_src[NE] +
  // m[NN*64] + h[NN*64]. CSR-build transients alias m/h (dead until gemm0):
  // pin = m (NCHUNK*NN = 25.6 MB exactly), pout = h.
  float* f        = (float*)d_ws;
  float* norm_out = f;
  float* norm_in  = f + NP;
  int*   row_ptr  = (int*)(f + 2 * NP);
  int*   cnt_in   = row_ptr + NP;
  int*   partial  = cnt_in + NP;
  int*   csr_src  = partial + 128;
  float* m        = (float*)(csr_src + NE);
  float* h        = m + NN * 64;
  int*   pin      = (int*)m;
  int*   pout     = (int*)h;

  // --- CSR build (dst-sorted) + norms: zero global atomics ---
  hist_lds_kernel<<<NSEG * NCHUNK, 1024, 0, stream>>>(edst, pin);
  hist_lds_kernel<<<NSEG * NCHUNK, 1024, 0, stream>>>(esrc, pout);
  merge_kernel<<<(NN + 255) / 256, 256, 0, stream>>>(pin, pout, cnt_in, norm_out, norm_in);
  chunk_sum_kernel<<<NBLK, 256, 0, stream>>>(cnt_in, partial);
  partial_scan_kernel<<<1, 128, 0, stream>>>(partial);
  chunk_scan_kernel<<<NBLK, 256, 0, stream>>>(cnt_in, partial, row_ptr);
  fill_lds_kernel<<<NSEG * NCHUNK, 1024, 0, stream>>>(esrc, edst, row_ptr, pin, csr_src);

  const int gb = (NN + 63) / 64;
  const int gg = (NN + 3) / 4;

  // Layer 0: m = (x*norm_out) @ W0 ; h = relu(agg*norm_in + b0)*norm_out
  gemm_kernel<128, 64, true><<<gb, 256, 0, stream>>>(x, W0, norm_out, m);
  gather_kernel<64, true><<<gg, 256, 0, stream>>>(m, row_ptr, csr_src, norm_in, norm_out, b0, h);

  // Layer 1: m = h @ W1 ; h = relu(agg*norm_in + b1)*norm_out
  gemm_kernel<64, 64, false><<<gb, 256, 0, stream>>>(h, W1, nullptr, m);
  gather_kernel<64, true><<<gg, 256, 0, stream>>>(m, row_ptr, csr_src, norm_in, norm_out, b1, h);

  // Layer 2: m = h @ W2 (40 cols) ; out = agg*norm_in + b2
  gemm_kernel<64, 40, false><<<gb, 256, 0, stream>>>(h, W2, nullptr, m);
  gather_kernel<40, false><<<gg, 256, 0, stream>>>(m, row_ptr, csr_src, norm_in, norm_out, b2, out);
}

// Round 9
// 301.719 us; speedup vs baseline: 1.3288x; 1.0466x over previous
//
#include <hip/hip_runtime.h>
#include <hip/hip_fp16.h>

// GraphConv 3-layer GCN: N=100000 nodes, E=1280000 edges; dims 128->64->64->40.
constexpr int NN = 100000;
constexpr int NE = 1280000;
constexpr int NP = 100352;       // padded N (= 98 * 1024)
constexpr int NBLK = NP / 1024;  // 98 scan chunks

// LDS-segmented histogram geometry.
constexpr int SEGSZ = 16384;                  // 64 KB of int bins per block
constexpr int NSEG = 7;                       // 7*16384 = 114688 >= NN
constexpr int NCHUNK = 64;                    // edge chunks
constexpr int CHSZ = NE / NCHUNK;             // 20000 (exact)

// ---------------------------------------------------------------------------
// Histogram of vals[] (node ids) into partial[c][n] (stride NN), via LDS bins.
// ---------------------------------------------------------------------------
__global__ __launch_bounds__(1024) void hist_lds_kernel(
    const int* __restrict__ vals, int* __restrict__ partial) {
  __shared__ int hcnt[SEGSZ];
  const int s = blockIdx.x % NSEG, c = blockIdx.x / NSEG;
  const int t = threadIdx.x;
#pragma unroll 4
  for (int i = t; i < SEGSZ; i += 1024) hcnt[i] = 0;
  __syncthreads();
  const int lo = s * SEGSZ;
  const int beg = c * CHSZ;
  for (int e = beg + t; e < beg + CHSZ; e += 1024) {
    unsigned v = (unsigned)(vals[e] - lo);
    if (v < (unsigned)SEGSZ) atomicAdd(&hcnt[v], 1);  // LDS atomic
  }
  __syncthreads();
  int* p = partial + (size_t)c * NN;
#pragma unroll 4
  for (int i = t; i < SEGSZ; i += 1024) {
    int n = lo + i;
    if (n < NN) p[n] = hcnt[i];
  }
}

// ---------------------------------------------------------------------------
// Merge chunk-partials per node: cnt_in = sum, pin <- exclusive chunk prefix
// (in place, consumed by fill), norms from both degree sums.
// ---------------------------------------------------------------------------
__global__ __launch_bounds__(256) void merge_kernel(
    int* __restrict__ pin, const int* __restrict__ pout,
    int* __restrict__ cnt_in, float* __restrict__ norm_out,
    float* __restrict__ norm_in) {
  int n = blockIdx.x * 256 + threadIdx.x;
  if (n >= NN) return;
  int run = 0;
#pragma unroll 8
  for (int c = 0; c < NCHUNK; ++c) {
    size_t idx = (size_t)c * NN + n;
    int v = pin[idx];
    pin[idx] = run;
    run += v;
  }
  cnt_in[n] = run;
  int s = 0;
#pragma unroll 8
  for (int c = 0; c < NCHUNK; ++c) s += pout[(size_t)c * NN + n];
  norm_in[n]  = rsqrtf(fmaxf((float)run, 1.0f));
  norm_out[n] = rsqrtf(fmaxf((float)s, 1.0f));
}

// ---------------------------------------------------------------------------
// Two-level exclusive scan of cnt_in -> row_ptr
// ---------------------------------------------------------------------------
__global__ __launch_bounds__(256) void chunk_sum_kernel(
    const int* __restrict__ cnt, int* __restrict__ partial) {
  int t = threadIdx.x;
  int base = blockIdx.x * 1024 + t * 4;
  int s = 0;
#pragma unroll
  for (int j = 0; j < 4; ++j) {
    int gi = base + j;
    s += (gi < NN) ? cnt[gi] : 0;
  }
  __shared__ int r[256];
  r[t] = s;
  __syncthreads();
  for (int off = 128; off > 0; off >>= 1) {
    if (t < off) r[t] += r[t + off];
    __syncthreads();
  }
  if (t == 0) partial[blockIdx.x] = r[0];
}

__global__ __launch_bounds__(128) void partial_scan_kernel(int* __restrict__ partial) {
  int t = threadIdx.x;
  int v = (t < NBLK) ? partial[t] : 0;
  __shared__ int s[128];
  s[t] = v;
  __syncthreads();
  for (int off = 1; off < 128; off <<= 1) {
    int add = (t >= off) ? s[t - off] : 0;
    __syncthreads();
    s[t] += add;
    __syncthreads();
  }
  if (t < NBLK) partial[t] = s[t] - v;  // exclusive
}

__global__ __launch_bounds__(256) void chunk_scan_kernel(
    const int* __restrict__ cnt, const int* __restrict__ partial,
    int* __restrict__ row_ptr) {
  int t = threadIdx.x;
  int base = blockIdx.x * 1024 + t * 4;
  int c[4];
#pragma unroll
  for (int j = 0; j < 4; ++j) {
    int gi = base + j;
    c[j] = (gi < NN) ? cnt[gi] : 0;
  }
  int tsum = c[0] + c[1] + c[2] + c[3];
  __shared__ int s[256];
  s[t] = tsum;
  __syncthreads();
  for (int off = 1; off < 256; off <<= 1) {
    int add = (t >= off) ? s[t - off] : 0;
    __syncthreads();
    s[t] += add;
    __syncthreads();
  }
  int run = s[t] - tsum + partial[blockIdx.x];
#pragma unroll
  for (int j = 0; j < 4; ++j) {
    int gi = base + j;
    if (gi <= NN) row_ptr[gi] = run;
    run += c[j];
  }
}

// ---------------------------------------------------------------------------
// CSR fill via LDS cursors (no device atomics).
// ---------------------------------------------------------------------------
__global__ __launch_bounds__(1024) void fill_lds_kernel(
    const int* __restrict__ src, const int* __restrict__ dst,
    const int* __restrict__ row_ptr, const int* __restrict__ pin,
    int* __restrict__ csr_src) {
  __shared__ int cur[SEGSZ];
  const int s = blockIdx.x % NSEG, c = blockIdx.x / NSEG;
  const int t = threadIdx.x;
  const int lo = s * SEGSZ;
  const int* base = pin + (size_t)c * NN;
#pragma unroll 4
  for (int i = t; i < SEGSZ; i += 1024) {
    int n = lo + i;
    cur[i] = (n < NN) ? (row_ptr[n] + base[n]) : 0;
  }
  __syncthreads();
  const int beg = c * CHSZ;
  for (int e = beg + t; e < beg + CHSZ; e += 1024) {
    unsigned d = (unsigned)(dst[e] - lo);
    if (d < (unsigned)SEGSZ) {
      int pos = atomicAdd(&cur[d], 1);  // LDS atomic
      csr_src[pos] = src[e];
    }
  }
}

// ---------------------------------------------------------------------------
// GEMM:  m[row, :] = fp16( PRE(in[row, :]) @ W )   (PRE = *norm_out if SCALE)
// 64x64 tile, 4x4 micro-tile, W per-32-K chunk in LDS (16.6 KB total),
// launch_bounds(256,4) = 128-VGPR budget (no spill; (256,8) spilled in R7).
// Output is fp16 (halves the gather's L2-miss bytes downstream).
// ---------------------------------------------------------------------------
template <int K, int COLS, bool SCALE>
__global__ __launch_bounds__(256, 4) void gemm_kernel(
    const float* __restrict__ in, const float* __restrict__ W,
    const float* __restrict__ norm_out, __half* __restrict__ out) {
  constexpr int KC = 32;
  constexpr int XS = 68;  // 64 rows + pad; 68*4B = 272B, 16B-aligned rows
  __shared__ float Wl[KC][64];
  __shared__ float xt[KC][XS];

  const int tid = threadIdx.x;
  const int tc = tid & 15;   // col group: cols 4*tc .. 4*tc+3
  const int tr = tid >> 4;   // row group: rows 4*tr .. 4*tr+3
  const int row0 = blockIdx.x * 64;

  // Zero-pad Wl cols >= COLS once (visible after first in-loop barrier)
  if constexpr (COLS < 64) {
    for (int i = tid; i < KC * 64; i += 256) {
      int k = i >> 6, c = i & 63;
      if (c >= COLS) Wl[k][c] = 0.0f;
    }
  }

  float acc[4][4] = {};

  for (int kc = 0; kc < K; kc += KC) {
    // Stage W chunk via float4 (rows are 4-float-aligned for COLS=64/40)
    constexpr int CV = COLS / 4;       // 16 or 10
    constexpr int WV = KC * CV;        // 512 or 320
    for (int i = tid; i < WV; i += 256) {
      int k = i / CV, c4 = i - k * CV;
      float4 wv = *(const float4*)&W[(size_t)(kc + k) * COLS + 4 * c4];
      *(float4*)&Wl[k][4 * c4] = wv;
    }
    // Stage x chunk transposed via float4 loads
#pragma unroll
    for (int i = 0; i < 2; ++i) {
      int q = i * 256 + tid;
      int r = q >> 3;
      int k4 = q & 7;
      int grow = row0 + r;
      float4 v = {0.f, 0.f, 0.f, 0.f};
      if (grow < NN) {
        v = *(const float4*)&in[(size_t)grow * K + kc + 4 * k4];
        if constexpr (SCALE) {
          float no = norm_out[grow];
          v.x *= no; v.y *= no; v.z *= no; v.w *= no;
        }
      }
      xt[4 * k4 + 0][r] = v.x;
      xt[4 * k4 + 1][r] = v.y;
      xt[4 * k4 + 2][r] = v.z;
      xt[4 * k4 + 3][r] = v.w;
    }
    __syncthreads();
#pragma unroll
    for (int kk = 0; kk < KC; ++kk) {
      float4 xv = *(const float4*)&xt[kk][4 * tr];
      float4 wv = *(const float4*)&Wl[kk][4 * tc];
      float xa[4] = {xv.x, xv.y, xv.z, xv.w};
      float wa[4] = {wv.x, wv.y, wv.z, wv.w};
#pragma unroll
      for (int r = 0; r < 4; ++r)
#pragma unroll
        for (int c = 0; c < 4; ++c)
          acc[r][c] = fmaf(xa[r], wa[c], acc[r][c]);
    }
    __syncthreads();
  }

  // Epilogue: pack 4 cols -> 2x half2 (8 B, aligned: COLS*2B rows, 8B steps)
  if (4 * tc < COLS) {
#pragma unroll
    for (int r = 0; r < 4; ++r) {
      int grow = row0 + 4 * tr + r;
      if (grow < NN) {
        __half2 h0 = __floats2half2_rn(acc[r][0], acc[r][1]);
        __half2 h1 = __floats2half2_rn(acc[r][2], acc[r][3]);
        uint2 st = {*(unsigned*)&h0, *(unsigned*)&h1};
        *(uint2*)&out[(size_t)grow * COLS + 4 * tc] = st;
      }
    }
  }
}

// ---------------------------------------------------------------------------
// CSR gather from fp16 m: one wave per node, 4-edge groups x 16 lanes,
// each lane loads 4 halfs (8 B) per edge row; accumulate fp32.
// RELU: out = relu(acc*norm_in + bias)*norm_out (fp32 h); else acc*norm_in+bias.
// ---------------------------------------------------------------------------
template <int C, bool RELU>
__global__ __launch_bounds__(256) void gather_kernel(
    const __half* __restrict__ m, const int* __restrict__ row_ptr,
    const int* __restrict__ csr_src, const float* __restrict__ norm_in,
    const float* __restrict__ norm_out, const float* __restrict__ bias,
    float* __restrict__ outp) {
  constexpr int CV = C / 4;  // 4-half groups per row: 16 (C=64), 10 (C=40)
  const int node = blockIdx.x * 4 + (threadIdx.x >> 6);
  const int lane = threadIdx.x & 63;
  if (node >= NN) return;
  const int beg = row_ptr[node];
  const int end = row_ptr[node + 1];
  const int eg = lane >> 4;
  const int fl = lane & 15;
  const uint2* m2 = (const uint2*)m;  // 8 B = 4 halfs

  float4 acc = {0.f, 0.f, 0.f, 0.f};
#pragma unroll 4
  for (int i = beg + eg; i < end; i += 4) {
    int s = csr_src[i];
    if (fl < CV) {
      uint2 v = m2[(size_t)s * CV + fl];
      float2 f01 = __half22float2(*(const __half2*)&v.x);
      float2 f23 = __half22float2(*(const __half2*)&v.y);
      acc.x += f01.x; acc.y += f01.y; acc.z += f23.x; acc.w += f23.y;
    }
  }
  acc.x += __shfl_xor(acc.x, 16); acc.y += __shfl_xor(acc.y, 16);
  acc.z += __shfl_xor(acc.z, 16); acc.w += __shfl_xor(acc.w, 16);
  acc.x += __shfl_xor(acc.x, 32); acc.y += __shfl_xor(acc.y, 32);
  acc.z += __shfl_xor(acc.z, 32); acc.w += __shfl_xor(acc.w, 32);

  if (eg == 0 && fl < CV) {
    float ni = norm_in[node];
    float4 b4 = ((const float4*)bias)[fl];
    float4 r;
    r.x = fmaf(acc.x, ni, b4.x);
    r.y = fmaf(acc.y, ni, b4.y);
    r.z = fmaf(acc.z, ni, b4.z);
    r.w = fmaf(acc.w, ni, b4.w);
    if constexpr (RELU) {
      float no = norm_out[node];
      r.x = fmaxf(r.x, 0.f) * no;
      r.y = fmaxf(r.y, 0.f) * no;
      r.z = fmaxf(r.z, 0.f) * no;
      r.w = fmaxf(r.w, 0.f) * no;
    }
    ((float4*)outp)[(size_t)node * CV + fl] = r;
  }
}

// ---------------------------------------------------------------------------
extern "C" void kernel_launch(void* const* d_in, const int* in_sizes, int n_in,
                              void* d_out, int out_size, void* d_ws, size_t ws_size,
                              hipStream_t stream) {
  const float* x    = (const float*)d_in[0];
  const float* W0   = (const float*)d_in[1];
  const float* b0   = (const float*)d_in[2];
  const float* W1   = (const float*)d_in[3];
  const float* b1   = (const float*)d_in[4];
  const float* W2   = (const float*)d_in[5];
  const float* b2   = (const float*)d_in[6];
  const int*   esrc = (const int*)d_in[7];
  const int*   edst = (const int*)d_in[8];
  float* out = (float*)d_out;

  // Workspace (4B units): norms/row_ptr/cnt_in/partial + csr_src[NE] +
  // m-region[NN*64 floats] + h[NN*64 floats].
  // m (fp16, NN*64 halfs = 12.8 MB) lives in the first half of the m-region.
  // CSR-build transients alias m-region/h (dead until gemm0):
  //   pin = m-region (NCHUNK*NN ints = 25.6 MB exactly), pout = h.
  float*  f        = (float*)d_ws;
  float*  norm_out = f;
  float*  norm_in  = f + NP;
  int*    row_ptr  = (int*)(f + 2 * NP);
  int*    cnt_in   = row_ptr + NP;
  int*    partial  = cnt_in + NP;
  int*    csr_src  = partial + 128;
  float*  mreg     = (float*)(csr_src + NE);
  float*  h        = mreg + NN * 64;
  __half* m        = (__half*)mreg;
  int*    pin      = (int*)mreg;
  int*    pout     = (int*)h;

  // --- CSR build (dst-sorted) + norms: zero global atomics ---
  hist_lds_kernel<<<NSEG * NCHUNK, 1024, 0, stream>>>(edst, pin);
  hist_lds_kernel<<<NSEG * NCHUNK, 1024, 0, stream>>>(esrc, pout);
  merge_kernel<<<(NN + 255) / 256, 256, 0, stream>>>(pin, pout, cnt_in, norm_out, norm_in);
  chunk_sum_kernel<<<NBLK, 256, 0, stream>>>(cnt_in, partial);
  partial_scan_kernel<<<1, 128, 0, stream>>>(partial);
  chunk_scan_kernel<<<NBLK, 256, 0, stream>>>(cnt_in, partial, row_ptr);
  fill_lds_kernel<<<NSEG * NCHUNK, 1024, 0, stream>>>(esrc, edst, row_ptr, pin, csr_src);

  const int gb = (NN + 63) / 64;
  const int gg = (NN + 3) / 4;

  // Layer 0: m = fp16((x*norm_out) @ W0) ; h = relu(agg*norm_in + b0)*norm_out
  gemm_kernel<128, 64, true><<<gb, 256, 0, stream>>>(x, W0, norm_out, m);
  gather_kernel<64, true><<<gg, 256, 0, stream>>>(m, row_ptr, csr_src, norm_in, norm_out, b0, h);

  // Layer 1: m = fp16(h @ W1) ; h = relu(agg*norm_in + b1)*norm_out
  gemm_kernel<64, 64, false><<<gb, 256, 0, stream>>>(h, W1, nullptr, m);
  gather_kernel<64, true><<<gg, 256, 0, stream>>>(m, row_ptr, csr_src, norm_in, norm_out, b1, h);

  // Layer 2: m = fp16(h @ W2) (40 cols) ; out = agg*norm_in + b2
  gemm_kernel<64, 40, false><<<gb, 256, 0, stream>>>(h, W2, nullptr, m);
  gather_kernel<40, false><<<gg, 256, 0, stream>>>(m, row_ptr, csr_src, norm_in, norm_out, b2, out);
}

// Round 11
// 268.901 us; speedup vs baseline: 1.4910x; 1.1220x over previous
//
#include <hip/hip_runtime.h>
#include <hip/hip_fp16.h>

// GraphConv 3-layer GCN: N=100000 nodes, E=1280000 edges; dims 128->64->64->40.
constexpr int NN = 100000;
constexpr int NE = 1280000;
constexpr int NP = 100352;       // padded N (= 98 * 1024)
constexpr int NBLK = NP / 1024;  // 98 scan chunks

// LDS-segmented histogram geometry.
constexpr int SEGSZ = 16384;                  // 64 KB of int bins per block
constexpr int NSEG = 7;                       // 7*16384 = 114688 >= NN
constexpr int NCHUNK = 64;                    // edge chunks
constexpr int CHSZ = NE / NCHUNK;             // 20000 (exact)

// ---------------------------------------------------------------------------
// Histogram of vals[] (node ids) into partial[c][n] (stride NN), via LDS bins.
// ---------------------------------------------------------------------------
__global__ __launch_bounds__(1024) void hist_lds_kernel(
    const int* __restrict__ vals, int* __restrict__ partial) {
  __shared__ int hcnt[SEGSZ];
  const int s = blockIdx.x % NSEG, c = blockIdx.x / NSEG;
  const int t = threadIdx.x;
#pragma unroll 4
  for (int i = t; i < SEGSZ; i += 1024) hcnt[i] = 0;
  __syncthreads();
  const int lo = s * SEGSZ;
  const int beg = c * CHSZ;
  for (int e = beg + t; e < beg + CHSZ; e += 1024) {
    unsigned v = (unsigned)(vals[e] - lo);
    if (v < (unsigned)SEGSZ) atomicAdd(&hcnt[v], 1);  // LDS atomic
  }
  __syncthreads();
  int* p = partial + (size_t)c * NN;
#pragma unroll 4
  for (int i = t; i < SEGSZ; i += 1024) {
    int n = lo + i;
    if (n < NN) p[n] = hcnt[i];
  }
}

// ---------------------------------------------------------------------------
// Merge chunk-partials per node: cnt_in = sum, pin <- exclusive chunk prefix
// (in place, consumed by fill), norms from both degree sums.
// ---------------------------------------------------------------------------
__global__ __launch_bounds__(256) void merge_kernel(
    int* __restrict__ pin, const int* __restrict__ pout,
    int* __restrict__ cnt_in, float* __restrict__ norm_out,
    float* __restrict__ norm_in) {
  int n = blockIdx.x * 256 + threadIdx.x;
  if (n >= NN) return;
  int run = 0;
#pragma unroll 8
  for (int c = 0; c < NCHUNK; ++c) {
    size_t idx = (size_t)c * NN + n;
    int v = pin[idx];
    pin[idx] = run;
    run += v;
  }
  cnt_in[n] = run;
  int s = 0;
#pragma unroll 8
  for (int c = 0; c < NCHUNK; ++c) s += pout[(size_t)c * NN + n];
  norm_in[n]  = rsqrtf(fmaxf((float)run, 1.0f));
  norm_out[n] = rsqrtf(fmaxf((float)s, 1.0f));
}

// ---------------------------------------------------------------------------
// Two-level exclusive scan of cnt_in -> row_ptr
// ---------------------------------------------------------------------------
__global__ __launch_bounds__(256) void chunk_sum_kernel(
    const int* __restrict__ cnt, int* __restrict__ partial) {
  int t = threadIdx.x;
  int base = blockIdx.x * 1024 + t * 4;
  int s = 0;
#pragma unroll
  for (int j = 0; j < 4; ++j) {
    int gi = base + j;
    s += (gi < NN) ? cnt[gi] : 0;
  }
  __shared__ int r[256];
  r[t] = s;
  __syncthreads();
  for (int off = 128; off > 0; off >>= 1) {
    if (t < off) r[t] += r[t + off];
    __syncthreads();
  }
  if (t == 0) partial[blockIdx.x] = r[0];
}

__global__ __launch_bounds__(128) void partial_scan_kernel(int* __restrict__ partial) {
  int t = threadIdx.x;
  int v = (t < NBLK) ? partial[t] : 0;
  __shared__ int s[128];
  s[t] = v;
  __syncthreads();
  for (int off = 1; off < 128; off <<= 1) {
    int add = (t >= off) ? s[t - off] : 0;
    __syncthreads();
    s[t] += add;
    __syncthreads();
  }
  if (t < NBLK) partial[t] = s[t] - v;  // exclusive
}

__global__ __launch_bounds__(256) void chunk_scan_kernel(
    const int* __restrict__ cnt, const int* __restrict__ partial,
    int* __restrict__ row_ptr) {
  int t = threadIdx.x;
  int base = blockIdx.x * 1024 + t * 4;
  int c[4];
#pragma unroll
  for (int j = 0; j < 4; ++j) {
    int gi = base + j;
    c[j] = (gi < NN) ? cnt[gi] : 0;
  }
  int tsum = c[0] + c[1] + c[2] + c[3];
  __shared__ int s[256];
  s[t] = tsum;
  __syncthreads();
  for (int off = 1; off < 256; off <<= 1) {
    int add = (t >= off) ? s[t - off] : 0;
    __syncthreads();
    s[t] += add;
    __syncthreads();
  }
  int run = s[t] - tsum + partial[blockIdx.x];
#pragma unroll
  for (int j = 0; j < 4; ++j) {
    int gi = base + j;
    if (gi <= NN) row_ptr[gi] = run;
    run += c[j];
  }
}

// ---------------------------------------------------------------------------
// CSR fill via LDS cursors (no device atomics).
// ---------------------------------------------------------------------------
__global__ __launch_bounds__(1024) void fill_lds_kernel(
    const int* __restrict__ src, const int* __restrict__ dst,
    const int* __restrict__ row_ptr, const int* __restrict__ pin,
    int* __restrict__ csr_src) {
  __shared__ int cur[SEGSZ];
  const int s = blockIdx.x % NSEG, c = blockIdx.x / NSEG;
  const int t = threadIdx.x;
  const int lo = s * SEGSZ;
  const int* base = pin + (size_t)c * NN;
#pragma unroll 4
  for (int i = t; i < SEGSZ; i += 1024) {
    int n = lo + i;
    cur[i] = (n < NN) ? (row_ptr[n] + base[n]) : 0;
  }
  __syncthreads();
  const int beg = c * CHSZ;
  for (int e = beg + t; e < beg + CHSZ; e += 1024) {
    unsigned d = (unsigned)(dst[e] - lo);
    if (d < (unsigned)SEGSZ) {
      int pos = atomicAdd(&cur[d], 1);  // LDS atomic
      csr_src[pos] = src[e];
    }
  }
}

// ---------------------------------------------------------------------------
// GEMM:  m[row, :] = fp16( PRE(in[row, :]) @ W )   (PRE = *norm_out if SCALE)
// 64x64 tile, 4x4 micro-tile, W per-32-K chunk in LDS, launch_bounds(256,4)
// (128-VGPR budget; (256,8) spilled in R7). fp16 output for the gather.
// ---------------------------------------------------------------------------
template <int K, int COLS, bool SCALE>
__global__ __launch_bounds__(256, 4) void gemm_kernel(
    const float* __restrict__ in, const float* __restrict__ W,
    const float* __restrict__ norm_out, __half* __restrict__ out) {
  constexpr int KC = 32;
  constexpr int XS = 68;  // 64 rows + pad; 68*4B = 272B, 16B-aligned rows
  __shared__ float Wl[KC][64];
  __shared__ float xt[KC][XS];

  const int tid = threadIdx.x;
  const int tc = tid & 15;   // col group: cols 4*tc .. 4*tc+3
  const int tr = tid >> 4;   // row group: rows 4*tr .. 4*tr+3
  const int row0 = blockIdx.x * 64;

  if constexpr (COLS < 64) {
    for (int i = tid; i < KC * 64; i += 256) {
      int k = i >> 6, c = i & 63;
      if (c >= COLS) Wl[k][c] = 0.0f;
    }
  }

  float acc[4][4] = {};

  for (int kc = 0; kc < K; kc += KC) {
    constexpr int CV = COLS / 4;       // 16 or 10
    constexpr int WV = KC * CV;        // 512 or 320
    for (int i = tid; i < WV; i += 256) {
      int k = i / CV, c4 = i - k * CV;
      float4 wv = *(const float4*)&W[(size_t)(kc + k) * COLS + 4 * c4];
      *(float4*)&Wl[k][4 * c4] = wv;
    }
#pragma unroll
    for (int i = 0; i < 2; ++i) {
      int q = i * 256 + tid;
      int r = q >> 3;
      int k4 = q & 7;
      int grow = row0 + r;
      float4 v = {0.f, 0.f, 0.f, 0.f};
      if (grow < NN) {
        v = *(const float4*)&in[(size_t)grow * K + kc + 4 * k4];
        if constexpr (SCALE) {
          float no = norm_out[grow];
          v.x *= no; v.y *= no; v.z *= no; v.w *= no;
        }
      }
      xt[4 * k4 + 0][r] = v.x;
      xt[4 * k4 + 1][r] = v.y;
      xt[4 * k4 + 2][r] = v.z;
      xt[4 * k4 + 3][r] = v.w;
    }
    __syncthreads();
#pragma unroll
    for (int kk = 0; kk < KC; ++kk) {
      float4 xv = *(const float4*)&xt[kk][4 * tr];
      float4 wv = *(const float4*)&Wl[kk][4 * tc];
      float xa[4] = {xv.x, xv.y, xv.z, xv.w};
      float wa[4] = {wv.x, wv.y, wv.z, wv.w};
#pragma unroll
      for (int r = 0; r < 4; ++r)
#pragma unroll
        for (int c = 0; c < 4; ++c)
          acc[r][c] = fmaf(xa[r], wa[c], acc[r][c]);
    }
    __syncthreads();
  }

  if (4 * tc < COLS) {
#pragma unroll
    for (int r = 0; r < 4; ++r) {
      int grow = row0 + 4 * tr + r;
      if (grow < NN) {
        __half2 h0 = __floats2half2_rn(acc[r][0], acc[r][1]);
        __half2 h1 = __floats2half2_rn(acc[r][2], acc[r][3]);
        uint2 st = {*(unsigned*)&h0, *(unsigned*)&h1};
        *(uint2*)&out[(size_t)grow * COLS + 4 * tc] = st;
      }
    }
  }
}

// ---------------------------------------------------------------------------
// CSR gather from fp16 m — latency-optimized, 8 edge-groups x 8 lanes x uint4.
// R10 BUG FIX: the __shfl loop now has a WAVE-UNIFORM trip count. R10's
// per-group trip counts made source lanes exec-inactive at the tail
// iteration (deg=9,17,18,...) and __shfl from an inactive lane is undefined
// on gfx950 -> wrong row gathered (absmax 0.065). Rule: any __shfl in a loop
// needs a uniform trip count; clamp the source lane and predicate the body.
// ---------------------------------------------------------------------------
template <int C, bool RELU>
__global__ __launch_bounds__(256) void gather_kernel(
    const __half* __restrict__ m, const int* __restrict__ row_ptr,
    const int* __restrict__ csr_src, const float* __restrict__ norm_in,
    const float* __restrict__ norm_out, const float* __restrict__ bias,
    float* __restrict__ outp) {
  constexpr int RV = C / 8;  // uint4 (8 halfs) per row: 8 (C=64), 5 (C=40)
  const int node = blockIdx.x * 4 + (threadIdx.x >> 6);
  const int lane = threadIdx.x & 63;
  if (node >= NN) return;
  const int beg = row_ptr[node];
  const int deg = row_ptr[node + 1] - beg;
  const int eg = lane >> 3;  // edge group 0..7
  const int fl = lane & 7;   // uint4 index within row
  const uint4* m4 = (const uint4*)m;

  float acc[8] = {};
  for (int base = 0; base < deg; base += 64) {
    const int nb = min(deg - base, 64);
    const int idx = (lane < nb) ? csr_src[beg + base + lane] : 0;
    const int kmax = (nb + 7) >> 3;          // wave-uniform trip count
    for (int k = 0; k < kmax; ++k) {
      int i = eg + 8 * k;
      int s = __shfl(idx, (i < nb) ? i : 0);  // all 64 lanes active here
      if (i < nb && fl < RV) {
        uint4 v = m4[(size_t)s * RV + fl];
        float2 f0 = __half22float2(*(const __half2*)&v.x);
        float2 f1 = __half22float2(*(const __half2*)&v.y);
        float2 f2 = __half22float2(*(const __half2*)&v.z);
        float2 f3 = __half22float2(*(const __half2*)&v.w);
        acc[0] += f0.x; acc[1] += f0.y; acc[2] += f1.x; acc[3] += f1.y;
        acc[4] += f2.x; acc[5] += f2.y; acc[6] += f3.x; acc[7] += f3.y;
      }
    }
  }
#pragma unroll
  for (int j = 0; j < 8; ++j) {
    acc[j] += __shfl_xor(acc[j], 8);
    acc[j] += __shfl_xor(acc[j], 16);
    acc[j] += __shfl_xor(acc[j], 32);
  }

  if (eg == 0 && fl < RV) {
    float ni = norm_in[node];
    float4 b0 = ((const float4*)bias)[2 * fl];
    float4 b1 = ((const float4*)bias)[2 * fl + 1];
    float4 r0, r1;
    r0.x = fmaf(acc[0], ni, b0.x); r0.y = fmaf(acc[1], ni, b0.y);
    r0.z = fmaf(acc[2], ni, b0.z); r0.w = fmaf(acc[3], ni, b0.w);
    r1.x = fmaf(acc[4], ni, b1.x); r1.y = fmaf(acc[5], ni, b1.y);
    r1.z = fmaf(acc[6], ni, b1.z); r1.w = fmaf(acc[7], ni, b1.w);
    if constexpr (RELU) {
      float no = norm_out[node];
      r0.x = fmaxf(r0.x, 0.f) * no; r0.y = fmaxf(r0.y, 0.f) * no;
      r0.z = fmaxf(r0.z, 0.f) * no; r0.w = fmaxf(r0.w, 0.f) * no;
      r1.x = fmaxf(r1.x, 0.f) * no; r1.y = fmaxf(r1.y, 0.f) * no;
      r1.z = fmaxf(r1.z, 0.f) * no; r1.w = fmaxf(r1.w, 0.f) * no;
    }
    float* o = &outp[(size_t)node * C + 8 * fl];
    *(float4*)o = r0;
    *(float4*)(o + 4) = r1;
  }
}

// ---------------------------------------------------------------------------
extern "C" void kernel_launch(void* const* d_in, const int* in_sizes, int n_in,
                              void* d_out, int out_size, void* d_ws, size_t ws_size,
                              hipStream_t stream) {
  const float* x    = (const float*)d_in[0];
  const float* W0   = (const float*)d_in[1];
  const float* b0   = (const float*)d_in[2];
  const float* W1   = (const float*)d_in[3];
  const float* b1   = (const float*)d_in[4];
  const float* W2   = (const float*)d_in[5];
  const float* b2   = (const float*)d_in[6];
  const int*   esrc = (const int*)d_in[7];
  const int*   edst = (const int*)d_in[8];
  float* out = (float*)d_out;

  // Workspace (4B units): norms/row_ptr/cnt_in/partial + csr_src[NE] +
  // m-region[NN*64 floats] + h[NN*64 floats].
  // m (fp16, NN*64 halfs = 12.8 MB) lives in the first half of the m-region.
  // CSR-build transients alias m-region/h (dead until gemm0):
  //   pin = m-region (NCHUNK*NN ints = 25.6 MB exactly), pout = h.
  float*  f        = (float*)d_ws;
  float*  norm_out = f;
  float*  norm_in  = f + NP;
  int*    row_ptr  = (int*)(f + 2 * NP);
  int*    cnt_in   = row_ptr + NP;
  int*    partial  = cnt_in + NP;
  int*    csr_src  = partial + 128;
  float*  mreg     = (float*)(csr_src + NE);
  float*  h        = mreg + NN * 64;
  __half* m        = (__half*)mreg;
  int*    pin      = (int*)mreg;
  int*    pout     = (int*)h;

  // --- CSR build (dst-sorted) + norms: zero global atomics ---
  hist_lds_kernel<<<NSEG * NCHUNK, 1024, 0, stream>>>(edst, pin);
  hist_lds_kernel<<<NSEG * NCHUNK, 1024, 0, stream>>>(esrc, pout);
  merge_kernel<<<(NN + 255) / 256, 256, 0, stream>>>(pin, pout, cnt_in, norm_out, norm_in);
  chunk_sum_kernel<<<NBLK, 256, 0, stream>>>(cnt_in, partial);
  partial_scan_kernel<<<1, 128, 0, stream>>>(partial);
  chunk_scan_kernel<<<NBLK, 256, 0, stream>>>(cnt_in, partial, row_ptr);
  fill_lds_kernel<<<NSEG * NCHUNK, 1024, 0, stream>>>(esrc, edst, row_ptr, pin, csr_src);

  const int gb = (NN + 63) / 64;
  const int gg = (NN + 3) / 4;

  // Layer 0: m = fp16((x*norm_out) @ W0) ; h = relu(agg*norm_in + b0)*norm_out
  gemm_kernel<128, 64, true><<<gb, 256, 0, stream>>>(x, W0, norm_out, m);
  gather_kernel<64, true><<<gg, 256, 0, stream>>>(m, row_ptr, csr_src, norm_in, norm_out, b0, h);

  // Layer 1: m = fp16(h @ W1) ; h = relu(agg*norm_in + b1)*norm_out
  gemm_kernel<64, 64, false><<<gb, 256, 0, stream>>>(h, W1, nullptr, m);
  gather_kernel<64, true><<<gg, 256, 0, stream>>>(m, row_ptr, csr_src, norm_in, norm_out, b1, h);

  // Layer 2: m = fp16(h @ W2) (40 cols) ; out = agg*norm_in + b2
  gemm_kernel<64, 40, false><<<gb, 256, 0, stream>>>(h, W2, nullptr, m);
  gather_kernel<40, false><<<gg, 256, 0, stream>>>(m, row_ptr, csr_src, norm_in, norm_out, b2, out);
}

// Round 12
// 267.599 us; speedup vs baseline: 1.4982x; 1.0049x over previous
//
#include <hip/hip_runtime.h>
#include <hip/hip_fp16.h>

// GraphConv 3-layer GCN: N=100000 nodes, E=1280000 edges; dims 128->64->64->40.
constexpr int NN = 100000;
constexpr int NE = 1280000;
constexpr int NP = 100352;       // padded N (= 98 * 1024)
constexpr int NBLK = NP / 1024;  // 98 scan chunks

// LDS-segmented histogram geometry.
constexpr int SEGSZ = 16384;                  // 64 KB of int bins per block
constexpr int NSEG = 7;                       // 7*16384 = 114688 >= NN
constexpr int NCHUNK = 64;                    // edge chunks
constexpr int CHSZ = NE / NCHUNK;             // 20000 (exact)

// ---------------------------------------------------------------------------
// Histogram of vals[] (node ids) into partial[c][n] (stride NN), via LDS bins.
// ---------------------------------------------------------------------------
__global__ __launch_bounds__(1024) void hist_lds_kernel(
    const int* __restrict__ vals, int* __restrict__ partial) {
  __shared__ int hcnt[SEGSZ];
  const int s = blockIdx.x % NSEG, c = blockIdx.x / NSEG;
  const int t = threadIdx.x;
#pragma unroll 4
  for (int i = t; i < SEGSZ; i += 1024) hcnt[i] = 0;
  __syncthreads();
  const int lo = s * SEGSZ;
  const int beg = c * CHSZ;
  for (int e = beg + t; e < beg + CHSZ; e += 1024) {
    unsigned v = (unsigned)(vals[e] - lo);
    if (v < (unsigned)SEGSZ) atomicAdd(&hcnt[v], 1);  // LDS atomic
  }
  __syncthreads();
  int* p = partial + (size_t)c * NN;
#pragma unroll 4
  for (int i = t; i < SEGSZ; i += 1024) {
    int n = lo + i;
    if (n < NN) p[n] = hcnt[i];
  }
}

// ---------------------------------------------------------------------------
// Merge chunk-partials per node: cnt_in = sum, pin <- exclusive chunk prefix
// (in place, consumed by fill), norms from both degree sums.
// ---------------------------------------------------------------------------
__global__ __launch_bounds__(256) void merge_kernel(
    int* __restrict__ pin, const int* __restrict__ pout,
    int* __restrict__ cnt_in, float* __restrict__ norm_out,
    float* __restrict__ norm_in) {
  int n = blockIdx.x * 256 + threadIdx.x;
  if (n >= NN) return;
  int run = 0;
#pragma unroll 8
  for (int c = 0; c < NCHUNK; ++c) {
    size_t idx = (size_t)c * NN + n;
    int v = pin[idx];
    pin[idx] = run;
    run += v;
  }
  cnt_in[n] = run;
  int s = 0;
#pragma unroll 8
  for (int c = 0; c < NCHUNK; ++c) s += pout[(size_t)c * NN + n];
  norm_in[n]  = rsqrtf(fmaxf((float)run, 1.0f));
  norm_out[n] = rsqrtf(fmaxf((float)s, 1.0f));
}

// ---------------------------------------------------------------------------
// Two-level exclusive scan of cnt_in -> row_ptr
// ---------------------------------------------------------------------------
__global__ __launch_bounds__(256) void chunk_sum_kernel(
    const int* __restrict__ cnt, int* __restrict__ partial) {
  int t = threadIdx.x;
  int base = blockIdx.x * 1024 + t * 4;
  int s = 0;
#pragma unroll
  for (int j = 0; j < 4; ++j) {
    int gi = base + j;
    s += (gi < NN) ? cnt[gi] : 0;
  }
  __shared__ int r[256];
  r[t] = s;
  __syncthreads();
  for (int off = 128; off > 0; off >>= 1) {
    if (t < off) r[t] += r[t + off];
    __syncthreads();
  }
  if (t == 0) partial[blockIdx.x] = r[0];
}

__global__ __launch_bounds__(128) void partial_scan_kernel(int* __restrict__ partial) {
  int t = threadIdx.x;
  int v = (t < NBLK) ? partial[t] : 0;
  __shared__ int s[128];
  s[t] = v;
  __syncthreads();
  for (int off = 1; off < 128; off <<= 1) {
    int add = (t >= off) ? s[t - off] : 0;
    __syncthreads();
    s[t] += add;
    __syncthreads();
  }
  if (t < NBLK) partial[t] = s[t] - v;  // exclusive
}

__global__ __launch_bounds__(256) void chunk_scan_kernel(
    const int* __restrict__ cnt, const int* __restrict__ partial,
    int* __restrict__ row_ptr) {
  int t = threadIdx.x;
  int base = blockIdx.x * 1024 + t * 4;
  int c[4];
#pragma unroll
  for (int j = 0; j < 4; ++j) {
    int gi = base + j;
    c[j] = (gi < NN) ? cnt[gi] : 0;
  }
  int tsum = c[0] + c[1] + c[2] + c[3];
  __shared__ int s[256];
  s[t] = tsum;
  __syncthreads();
  for (int off = 1; off < 256; off <<= 1) {
    int add = (t >= off) ? s[t - off] : 0;
    __syncthreads();
    s[t] += add;
    __syncthreads();
  }
  int run = s[t] - tsum + partial[blockIdx.x];
#pragma unroll
  for (int j = 0; j < 4; ++j) {
    int gi = base + j;
    if (gi <= NN) row_ptr[gi] = run;
    run += c[j];
  }
}

// ---------------------------------------------------------------------------
// CSR fill via LDS cursors (no device atomics).
// ---------------------------------------------------------------------------
__global__ __launch_bounds__(1024) void fill_lds_kernel(
    const int* __restrict__ src, const int* __restrict__ dst,
    const int* __restrict__ row_ptr, const int* __restrict__ pin,
    int* __restrict__ csr_src) {
  __shared__ int cur[SEGSZ];
  const int s = blockIdx.x % NSEG, c = blockIdx.x / NSEG;
  const int t = threadIdx.x;
  const int lo = s * SEGSZ;
  const int* base = pin + (size_t)c * NN;
#pragma unroll 4
  for (int i = t; i < SEGSZ; i += 1024) {
    int n = lo + i;
    cur[i] = (n < NN) ? (row_ptr[n] + base[n]) : 0;
  }
  __syncthreads();
  const int beg = c * CHSZ;
  for (int e = beg + t; e < beg + CHSZ; e += 1024) {
    unsigned d = (unsigned)(dst[e] - lo);
    if (d < (unsigned)SEGSZ) {
      int pos = atomicAdd(&cur[d], 1);  // LDS atomic
      csr_src[pos] = src[e];
    }
  }
}

// ---------------------------------------------------------------------------
// GEMM:  m[row, :] = fp16( PRE(in[row, :]) @ W )   (PRE = *norm_out if SCALE)
// 64x64 tile, 4x4 micro-tile, W per-32-K chunk in LDS, launch_bounds(256,4)
// (128-VGPR budget; (256,8) spilled in R7). TIN = float (layer 0, x) or
// __half (layers 1/2 read fp16 h). fp16 output for the gather.
// ---------------------------------------------------------------------------
template <int K, int COLS, bool SCALE, typename TIN>
__global__ __launch_bounds__(256, 4) void gemm_kernel(
    const TIN* __restrict__ in, const float* __restrict__ W,
    const float* __restrict__ norm_out, __half* __restrict__ out) {
  constexpr int KC = 32;
  constexpr int XS = 68;  // 64 rows + pad; 68*4B = 272B, 16B-aligned rows
  __shared__ float Wl[KC][64];
  __shared__ float xt[KC][XS];

  const int tid = threadIdx.x;
  const int tc = tid & 15;   // col group: cols 4*tc .. 4*tc+3
  const int tr = tid >> 4;   // row group: rows 4*tr .. 4*tr+3
  const int row0 = blockIdx.x * 64;

  if constexpr (COLS < 64) {
    for (int i = tid; i < KC * 64; i += 256) {
      int k = i >> 6, c = i & 63;
      if (c >= COLS) Wl[k][c] = 0.0f;
    }
  }

  float acc[4][4] = {};

  for (int kc = 0; kc < K; kc += KC) {
    constexpr int CV = COLS / 4;       // 16 or 10
    constexpr int WV = KC * CV;        // 512 or 320
    for (int i = tid; i < WV; i += 256) {
      int k = i / CV, c4 = i - k * CV;
      float4 wv = *(const float4*)&W[(size_t)(kc + k) * COLS + 4 * c4];
      *(float4*)&Wl[k][4 * c4] = wv;
    }
    if constexpr (sizeof(TIN) == 4) {
      // fp32 input: 2 iters x float4 (4 floats/lane)
#pragma unroll
      for (int i = 0; i < 2; ++i) {
        int q = i * 256 + tid;
        int r = q >> 3;
        int k4 = q & 7;
        int grow = row0 + r;
        float4 v = {0.f, 0.f, 0.f, 0.f};
        if (grow < NN) {
          v = *(const float4*)&in[(size_t)grow * K + kc + 4 * k4];
          if constexpr (SCALE) {
            float no = norm_out[grow];
            v.x *= no; v.y *= no; v.z *= no; v.w *= no;
          }
        }
        xt[4 * k4 + 0][r] = v.x;
        xt[4 * k4 + 1][r] = v.y;
        xt[4 * k4 + 2][r] = v.z;
        xt[4 * k4 + 3][r] = v.w;
      }
    } else {
      // fp16 input: 1 iter x uint4 (8 halfs/lane); k4 = tid&3, r = tid>>2.
      // LDS write banks (68*8k4 = 0 mod 32): 4-way on 8 cheap writes - minor.
      int r = tid >> 2;
      int k4 = tid & 3;
      int grow = row0 + r;
      uint4 v = {0u, 0u, 0u, 0u};
      if (grow < NN)
        v = *(const uint4*)((const __half*)in + (size_t)grow * K + kc + 8 * k4);
      float2 f0 = __half22float2(*(const __half2*)&v.x);
      float2 f1 = __half22float2(*(const __half2*)&v.y);
      float2 f2 = __half22float2(*(const __half2*)&v.z);
      float2 f3 = __half22float2(*(const __half2*)&v.w);
      xt[8 * k4 + 0][r] = f0.x; xt[8 * k4 + 1][r] = f0.y;
      xt[8 * k4 + 2][r] = f1.x; xt[8 * k4 + 3][r] = f1.y;
      xt[8 * k4 + 4][r] = f2.x; xt[8 * k4 + 5][r] = f2.y;
      xt[8 * k4 + 6][r] = f3.x; xt[8 * k4 + 7][r] = f3.y;
    }
    __syncthreads();
#pragma unroll
    for (int kk = 0; kk < KC; ++kk) {
      float4 xv = *(const float4*)&xt[kk][4 * tr];
      float4 wv = *(const float4*)&Wl[kk][4 * tc];
      float xa[4] = {xv.x, xv.y, xv.z, xv.w};
      float wa[4] = {wv.x, wv.y, wv.z, wv.w};
#pragma unroll
      for (int r = 0; r < 4; ++r)
#pragma unroll
        for (int c = 0; c < 4; ++c)
          acc[r][c] = fmaf(xa[r], wa[c], acc[r][c]);
    }
    __syncthreads();
  }

  if (4 * tc < COLS) {
#pragma unroll
    for (int r = 0; r < 4; ++r) {
      int grow = row0 + 4 * tr + r;
      if (grow < NN) {
        __half2 h0 = __floats2half2_rn(acc[r][0], acc[r][1]);
        __half2 h1 = __floats2half2_rn(acc[r][2], acc[r][3]);
        uint2 st = {*(unsigned*)&h0, *(unsigned*)&h1};
        *(uint2*)&out[(size_t)grow * COLS + 4 * tc] = st;
      }
    }
  }
}

// ---------------------------------------------------------------------------
// CSR gather from fp16 m, 8 edge-groups x 8 lanes x uint4 (8 halfs).
// R11 showed VALUBusy 52% -> cut the VALU stream with packed fp16 adds:
// 4x v_pk_add_f16 per uint4 (vs 8 cvt + 8 add), flushed to fp32 once per
// 64-edge batch (<= 8 fp16 adds per flush -> error ~1e-3 pre-norm, safe).
// __shfl loop keeps the R11 wave-uniform trip count (R10 lesson).
// RELU: h stored fp16 (uint4 pack); final layer stores fp32 to d_out.
// ---------------------------------------------------------------------------
template <int C, bool RELU>
__global__ __launch_bounds__(256) void gather_kernel(
    const __half* __restrict__ m, const int* __restrict__ row_ptr,
    const int* __restrict__ csr_src, const float* __restrict__ norm_in,
    const float* __restrict__ norm_out, const float* __restrict__ bias,
    void* __restrict__ outp) {
  constexpr int RV = C / 8;  // uint4 (8 halfs) per row: 8 (C=64), 5 (C=40)
  const int node = blockIdx.x * 4 + (threadIdx.x >> 6);
  const int lane = threadIdx.x & 63;
  if (node >= NN) return;
  const int beg = row_ptr[node];
  const int deg = row_ptr[node + 1] - beg;
  const int eg = lane >> 3;  // edge group 0..7
  const int fl = lane & 7;   // uint4 index within row
  const uint4* m4 = (const uint4*)m;

  float acc[8] = {};
  for (int base = 0; base < deg; base += 64) {
    const int nb = min(deg - base, 64);
    const int idx = (lane < nb) ? csr_src[beg + base + lane] : 0;
    const int kmax = (nb + 7) >> 3;          // wave-uniform trip count
    __half2 z = __float2half2_rn(0.f);
    __half2 h0 = z, h1 = z, h2 = z, h3 = z;  // <= 8 adds before flush
    for (int k = 0; k < kmax; ++k) {
      int i = eg + 8 * k;
      int s = __shfl(idx, (i < nb) ? i : 0);  // all 64 lanes active here
      if (i < nb && fl < RV) {
        uint4 v = m4[(size_t)s * RV + fl];
        h0 = __hadd2(h0, *(const __half2*)&v.x);
        h1 = __hadd2(h1, *(const __half2*)&v.y);
        h2 = __hadd2(h2, *(const __half2*)&v.z);
        h3 = __hadd2(h3, *(const __half2*)&v.w);
      }
    }
    float2 f0 = __half22float2(h0), f1 = __half22float2(h1);
    float2 f2 = __half22float2(h2), f3 = __half22float2(h3);
    acc[0] += f0.x; acc[1] += f0.y; acc[2] += f1.x; acc[3] += f1.y;
    acc[4] += f2.x; acc[5] += f2.y; acc[6] += f3.x; acc[7] += f3.y;
  }
#pragma unroll
  for (int j = 0; j < 8; ++j) {
    acc[j] += __shfl_xor(acc[j], 8);
    acc[j] += __shfl_xor(acc[j], 16);
    acc[j] += __shfl_xor(acc[j], 32);
  }

  if (eg == 0 && fl < RV) {
    float ni = norm_in[node];
    float4 b0 = ((const float4*)bias)[2 * fl];
    float4 b1 = ((const float4*)bias)[2 * fl + 1];
    float r0[4], r1[4];
    r0[0] = fmaf(acc[0], ni, b0.x); r0[1] = fmaf(acc[1], ni, b0.y);
    r0[2] = fmaf(acc[2], ni, b0.z); r0[3] = fmaf(acc[3], ni, b0.w);
    r1[0] = fmaf(acc[4], ni, b1.x); r1[1] = fmaf(acc[5], ni, b1.y);
    r1[2] = fmaf(acc[6], ni, b1.z); r1[3] = fmaf(acc[7], ni, b1.w);
    if constexpr (RELU) {
      float no = norm_out[node];
#pragma unroll
      for (int j = 0; j < 4; ++j) {
        r0[j] = fmaxf(r0[j], 0.f) * no;
        r1[j] = fmaxf(r1[j], 0.f) * no;
      }
      __half2 p0 = __floats2half2_rn(r0[0], r0[1]);
      __half2 p1 = __floats2half2_rn(r0[2], r0[3]);
      __half2 p2 = __floats2half2_rn(r1[0], r1[1]);
      __half2 p3 = __floats2half2_rn(r1[2], r1[3]);
      uint4 st = {*(unsigned*)&p0, *(unsigned*)&p1,
                  *(unsigned*)&p2, *(unsigned*)&p3};
      ((uint4*)outp)[(size_t)node * RV + fl] = st;   // fp16 h
    } else {
      float* o = (float*)outp + (size_t)node * C + 8 * fl;
      float4 s0 = {r0[0], r0[1], r0[2], r0[3]};
      float4 s1 = {r1[0], r1[1], r1[2], r1[3]};
      *(float4*)o = s0;
      *(float4*)(o + 4) = s1;                        // fp32 final output
    }
  }
}

// ---------------------------------------------------------------------------
extern "C" void kernel_launch(void* const* d_in, const int* in_sizes, int n_in,
                              void* d_out, int out_size, void* d_ws, size_t ws_size,
                              hipStream_t stream) {
  const float* x    = (const float*)d_in[0];
  const float* W0   = (const float*)d_in[1];
  const float* b0   = (const float*)d_in[2];
  const float* W1   = (const float*)d_in[3];
  const float* b1   = (const float*)d_in[4];
  const float* W2   = (const float*)d_in[5];
  const float* b2   = (const float*)d_in[6];
  const int*   esrc = (const int*)d_in[7];
  const int*   edst = (const int*)d_in[8];
  float* out = (float*)d_out;

  // Workspace (4B units): norms/row_ptr/cnt_in/partial + csr_src[NE] +
  // m-region[NN*64 floats] + h-region[NN*64 floats].
  // m, h are fp16 (NN*64 halfs = 12.8 MB each) in the front of their regions.
  // CSR-build transients alias the regions (dead until gemm0):
  //   pin = m-region (NCHUNK*NN ints = 25.6 MB exactly), pout = h-region.
  float*  f        = (float*)d_ws;
  float*  norm_out = f;
  float*  norm_in  = f + NP;
  int*    row_ptr  = (int*)(f + 2 * NP);
  int*    cnt_in   = row_ptr + NP;
  int*    partial  = cnt_in + NP;
  int*    csr_src  = partial + 128;
  float*  mreg     = (float*)(csr_src + NE);
  float*  hreg     = mreg + NN * 64;
  __half* m        = (__half*)mreg;
  __half* h        = (__half*)hreg;
  int*    pin      = (int*)mreg;
  int*    pout     = (int*)hreg;

  // --- CSR build (dst-sorted) + norms: zero global atomics ---
  hist_lds_kernel<<<NSEG * NCHUNK, 1024, 0, stream>>>(edst, pin);
  hist_lds_kernel<<<NSEG * NCHUNK, 1024, 0, stream>>>(esrc, pout);
  merge_kernel<<<(NN + 255) / 256, 256, 0, stream>>>(pin, pout, cnt_in, norm_out, norm_in);
  chunk_sum_kernel<<<NBLK, 256, 0, stream>>>(cnt_in, partial);
  partial_scan_kernel<<<1, 128, 0, stream>>>(partial);
  chunk_scan_kernel<<<NBLK, 256, 0, stream>>>(cnt_in, partial, row_ptr);
  fill_lds_kernel<<<NSEG * NCHUNK, 1024, 0, stream>>>(esrc, edst, row_ptr, pin, csr_src);

  const int gb = (NN + 63) / 64;
  const int gg = (NN + 3) / 4;

  // Layer 0: m = fp16((x*norm_out) @ W0) ; h = fp16(relu(agg*ni + b0)*no)
  gemm_kernel<128, 64, true, float><<<gb, 256, 0, stream>>>(x, W0, norm_out, m);
  gather_kernel<64, true><<<gg, 256, 0, stream>>>(m, row_ptr, csr_src, norm_in, norm_out, b0, h);

  // Layer 1: m = fp16(h @ W1) ; h = fp16(relu(agg*ni + b1)*no)
  gemm_kernel<64, 64, false, __half><<<gb, 256, 0, stream>>>(h, W1, nullptr, m);
  gather_kernel<64, true><<<gg, 256, 0, stream>>>(m, row_ptr, csr_src, norm_in, norm_out, b1, h);

  // Layer 2: m = fp16(h @ W2) (40 cols) ; out = agg*ni + b2 (fp32)
  gemm_kernel<64, 40, false, __half><<<gb, 256, 0, stream>>>(h, W2, nullptr, m);
  gather_kernel<40, false><<<gg, 256, 0, stream>>>(m, row_ptr, csr_src, norm_in, norm_out, b2, out);
}

// Round 13
// 236.501 us; speedup vs baseline: 1.6952x; 1.1315x over previous
//
#include <hip/hip_runtime.h>
#include <hip/hip_fp16.h>

// GraphConv 3-layer GCN: N=100000 nodes, E=1280000 edges; dims 128->64->64->40.
constexpr int NN = 100000;
constexpr int NE = 1280000;
constexpr int NP = 100352;       // padded N (= 98 * 1024)
constexpr int NBLK = NP / 1024;  // 98 scan chunks

// LDS-segmented histogram geometry.
constexpr int SEGSZ = 16384;                  // 64 KB of int bins per block
constexpr int NSEG = 7;                       // 7*16384 = 114688 >= NN
constexpr int NCHUNK = 64;                    // edge chunks
constexpr int CHSZ = NE / NCHUNK;             // 20000 (exact)

// ---------------------------------------------------------------------------
// Histogram of vals[] (node ids) into partial[c][n] (stride NN), via LDS bins.
// ---------------------------------------------------------------------------
__global__ __launch_bounds__(1024) void hist_lds_kernel(
    const int* __restrict__ vals, int* __restrict__ partial) {
  __shared__ int hcnt[SEGSZ];
  const int s = blockIdx.x % NSEG, c = blockIdx.x / NSEG;
  const int t = threadIdx.x;
#pragma unroll 4
  for (int i = t; i < SEGSZ; i += 1024) hcnt[i] = 0;
  __syncthreads();
  const int lo = s * SEGSZ;
  const int beg = c * CHSZ;
  for (int e = beg + t; e < beg + CHSZ; e += 1024) {
    unsigned v = (unsigned)(vals[e] - lo);
    if (v < (unsigned)SEGSZ) atomicAdd(&hcnt[v], 1);  // LDS atomic
  }
  __syncthreads();
  int* p = partial + (size_t)c * NN;
#pragma unroll 4
  for (int i = t; i < SEGSZ; i += 1024) {
    int n = lo + i;
    if (n < NN) p[n] = hcnt[i];
  }
}

// ---------------------------------------------------------------------------
// Merge chunk-partials per node: cnt_in = sum, pin <- exclusive chunk prefix
// (in place, consumed by fill), norms from both degree sums.
// ---------------------------------------------------------------------------
__global__ __launch_bounds__(256) void merge_kernel(
    int* __restrict__ pin, const int* __restrict__ pout,
    int* __restrict__ cnt_in, float* __restrict__ norm_out,
    float* __restrict__ norm_in) {
  int n = blockIdx.x * 256 + threadIdx.x;
  if (n >= NN) return;
  int run = 0;
#pragma unroll 8
  for (int c = 0; c < NCHUNK; ++c) {
    size_t idx = (size_t)c * NN + n;
    int v = pin[idx];
    pin[idx] = run;
    run += v;
  }
  cnt_in[n] = run;
  int s = 0;
#pragma unroll 8
  for (int c = 0; c < NCHUNK; ++c) s += pout[(size_t)c * NN + n];
  norm_in[n]  = rsqrtf(fmaxf((float)run, 1.0f));
  norm_out[n] = rsqrtf(fmaxf((float)s, 1.0f));
}

// ---------------------------------------------------------------------------
// Two-level exclusive scan of cnt_in -> row_ptr
// ---------------------------------------------------------------------------
__global__ __launch_bounds__(256) void chunk_sum_kernel(
    const int* __restrict__ cnt, int* __restrict__ partial) {
  int t = threadIdx.x;
  int base = blockIdx.x * 1024 + t * 4;
  int s = 0;
#pragma unroll
  for (int j = 0; j < 4; ++j) {
    int gi = base + j;
    s += (gi < NN) ? cnt[gi] : 0;
  }
  __shared__ int r[256];
  r[t] = s;
  __syncthreads();
  for (int off = 128; off > 0; off >>= 1) {
    if (t < off) r[t] += r[t + off];
    __syncthreads();
  }
  if (t == 0) partial[blockIdx.x] = r[0];
}

__global__ __launch_bounds__(128) void partial_scan_kernel(int* __restrict__ partial) {
  int t = threadIdx.x;
  int v = (t < NBLK) ? partial[t] : 0;
  __shared__ int s[128];
  s[t] = v;
  __syncthreads();
  for (int off = 1; off < 128; off <<= 1) {
    int add = (t >= off) ? s[t - off] : 0;
    __syncthreads();
    s[t] += add;
    __syncthreads();
  }
  if (t < NBLK) partial[t] = s[t] - v;  // exclusive
}

__global__ __launch_bounds__(256) void chunk_scan_kernel(
    const int* __restrict__ cnt, const int* __restrict__ partial,
    int* __restrict__ row_ptr) {
  int t = threadIdx.x;
  int base = blockIdx.x * 1024 + t * 4;
  int c[4];
#pragma unroll
  for (int j = 0; j < 4; ++j) {
    int gi = base + j;
    c[j] = (gi < NN) ? cnt[gi] : 0;
  }
  int tsum = c[0] + c[1] + c[2] + c[3];
  __shared__ int s[256];
  s[t] = tsum;
  __syncthreads();
  for (int off = 1; off < 256; off <<= 1) {
    int add = (t >= off) ? s[t - off] : 0;
    __syncthreads();
    s[t] += add;
    __syncthreads();
  }
  int run = s[t] - tsum + partial[blockIdx.x];
#pragma unroll
  for (int j = 0; j < 4; ++j) {
    int gi = base + j;
    if (gi <= NN) row_ptr[gi] = run;
    run += c[j];
  }
}

// ---------------------------------------------------------------------------
// CSR fill via LDS cursors (no device atomics).
// ---------------------------------------------------------------------------
__global__ __launch_bounds__(1024) void fill_lds_kernel(
    const int* __restrict__ src, const int* __restrict__ dst,
    const int* __restrict__ row_ptr, const int* __restrict__ pin,
    int* __restrict__ csr_src) {
  __shared__ int cur[SEGSZ];
  const int s = blockIdx.x % NSEG, c = blockIdx.x / NSEG;
  const int t = threadIdx.x;
  const int lo = s * SEGSZ;
  const int* base = pin + (size_t)c * NN;
#pragma unroll 4
  for (int i = t; i < SEGSZ; i += 1024) {
    int n = lo + i;
    cur[i] = (n < NN) ? (row_ptr[n] + base[n]) : 0;
  }
  __syncthreads();
  const int beg = c * CHSZ;
  for (int e = beg + t; e < beg + CHSZ; e += 1024) {
    unsigned d = (unsigned)(dst[e] - lo);
    if (d < (unsigned)SEGSZ) {
      int pos = atomicAdd(&cur[d], 1);  // LDS atomic
      csr_src[pos] = src[e];
    }
  }
}

// ---------------------------------------------------------------------------
// GEMM:  m[row, :] = fp16( PRE(in[row, :]) @ W )   (PRE = *norm_out if SCALE)
// 64x64 tile, 4x4 micro-tile, W per-32-K chunk in LDS, launch_bounds(256,4)
// (128-VGPR budget; (256,8) spilled in R7). TIN = float (layer 0, x) or
// __half (layers 1/2 read fp16 h). fp16 output for the gather.
// ---------------------------------------------------------------------------
template <int K, int COLS, bool SCALE, typename TIN>
__global__ __launch_bounds__(256, 4) void gemm_kernel(
    const TIN* __restrict__ in, const float* __restrict__ W,
    const float* __restrict__ norm_out, __half* __restrict__ out) {
  constexpr int KC = 32;
  constexpr int XS = 68;  // 64 rows + pad; 68*4B = 272B, 16B-aligned rows
  __shared__ float Wl[KC][64];
  __shared__ float xt[KC][XS];

  const int tid = threadIdx.x;
  const int tc = tid & 15;   // col group: cols 4*tc .. 4*tc+3
  const int tr = tid >> 4;   // row group: rows 4*tr .. 4*tr+3
  const int row0 = blockIdx.x * 64;

  if constexpr (COLS < 64) {
    for (int i = tid; i < KC * 64; i += 256) {
      int k = i >> 6, c = i & 63;
      if (c >= COLS) Wl[k][c] = 0.0f;
    }
  }

  float acc[4][4] = {};

  for (int kc = 0; kc < K; kc += KC) {
    constexpr int CV = COLS / 4;       // 16 or 10
    constexpr int WV = KC * CV;        // 512 or 320
    for (int i = tid; i < WV; i += 256) {
      int k = i / CV, c4 = i - k * CV;
      float4 wv = *(const float4*)&W[(size_t)(kc + k) * COLS + 4 * c4];
      *(float4*)&Wl[k][4 * c4] = wv;
    }
    if constexpr (sizeof(TIN) == 4) {
      // fp32 input: 2 iters x float4 (4 floats/lane)
#pragma unroll
      for (int i = 0; i < 2; ++i) {
        int q = i * 256 + tid;
        int r = q >> 3;
        int k4 = q & 7;
        int grow = row0 + r;
        float4 v = {0.f, 0.f, 0.f, 0.f};
        if (grow < NN) {
          v = *(const float4*)&in[(size_t)grow * K + kc + 4 * k4];
          if constexpr (SCALE) {
            float no = norm_out[grow];
            v.x *= no; v.y *= no; v.z *= no; v.w *= no;
          }
        }
        xt[4 * k4 + 0][r] = v.x;
        xt[4 * k4 + 1][r] = v.y;
        xt[4 * k4 + 2][r] = v.z;
        xt[4 * k4 + 3][r] = v.w;
      }
    } else {
      // fp16 input: 1 iter x uint4 (8 halfs/lane); k4 = tid&3, r = tid>>2.
      int r = tid >> 2;
      int k4 = tid & 3;
      int grow = row0 + r;
      uint4 v = {0u, 0u, 0u, 0u};
      if (grow < NN)
        v = *(const uint4*)((const __half*)in + (size_t)grow * K + kc + 8 * k4);
      float2 f0 = __half22float2(*(const __half2*)&v.x);
      float2 f1 = __half22float2(*(const __half2*)&v.y);
      float2 f2 = __half22float2(*(const __half2*)&v.z);
      float2 f3 = __half22float2(*(const __half2*)&v.w);
      xt[8 * k4 + 0][r] = f0.x; xt[8 * k4 + 1][r] = f0.y;
      xt[8 * k4 + 2][r] = f1.x; xt[8 * k4 + 3][r] = f1.y;
      xt[8 * k4 + 4][r] = f2.x; xt[8 * k4 + 5][r] = f2.y;
      xt[8 * k4 + 6][r] = f3.x; xt[8 * k4 + 7][r] = f3.y;
    }
    __syncthreads();
#pragma unroll
    for (int kk = 0; kk < KC; ++kk) {
      float4 xv = *(const float4*)&xt[kk][4 * tr];
      float4 wv = *(const float4*)&Wl[kk][4 * tc];
      float xa[4] = {xv.x, xv.y, xv.z, xv.w};
      float wa[4] = {wv.x, wv.y, wv.z, wv.w};
#pragma unroll
      for (int r = 0; r < 4; ++r)
#pragma unroll
        for (int c = 0; c < 4; ++c)
          acc[r][c] = fmaf(xa[r], wa[c], acc[r][c]);
    }
    __syncthreads();
  }

  if (4 * tc < COLS) {
#pragma unroll
    for (int r = 0; r < 4; ++r) {
      int grow = row0 + 4 * tr + r;
      if (grow < NN) {
        __half2 h0 = __floats2half2_rn(acc[r][0], acc[r][1]);
        __half2 h1 = __floats2half2_rn(acc[r][2], acc[r][3]);
        uint2 st = {*(unsigned*)&h0, *(unsigned*)&h1};
        *(uint2*)&out[(size_t)grow * COLS + 4 * tc] = st;
      }
    }
  }
}

// ---------------------------------------------------------------------------
// CSR gather from fp16 m — TWO NODES PER WAVE (32 lanes each).
// R12 analysis: per-node FIXED cost (3-level reduction 48 instr + preamble/
// epilogue ~55) dominated at avg deg 12.8. Halving the per-node lane width:
//  * node = half-wave; 4 edge-groups x 8 uint4-lanes per node
//  * __shfl width=32 keeps index distribution inside the half; every shfl
//    source lane is exec-active (uniform trip per half — R10 rule holds)
//  * reduction: 2 levels (xor 8, 16), both within the half: 8 instr/node
//  * preamble/epilogue amortized over 2 nodes per wave
// Packed fp16 inner adds kept (<=8 adds per flush -> error ~1e-3, safe).
// ---------------------------------------------------------------------------
template <int C, bool RELU>
__global__ __launch_bounds__(256) void gather_kernel(
    const __half* __restrict__ m, const int* __restrict__ row_ptr,
    const int* __restrict__ csr_src, const float* __restrict__ norm_in,
    const float* __restrict__ norm_out, const float* __restrict__ bias,
    void* __restrict__ outp) {
  constexpr int RV = C / 8;            // uint4 per row: 8 (C=64), 5 (C=40)
  constexpr unsigned RB = C * 2;       // row bytes: 128 or 80
  const int node = blockIdx.x * 8 + (threadIdx.x >> 5);
  const int l32 = threadIdx.x & 31;    // lane within half-wave
  if (node >= NN) return;
  const int beg = row_ptr[node];
  const int deg = row_ptr[node + 1] - beg;
  const int eg = l32 >> 3;             // edge group 0..3
  const int fl = l32 & 7;              // uint4 index within row
  const char* mb = (const char*)m;
  const unsigned fb = (unsigned)fl * 16u;

  float acc[8] = {};
  for (int base = 0; base < deg; base += 32) {
    const int nb = min(deg - base, 32);
    const int idx = (l32 < nb) ? csr_src[beg + base + l32] : 0;
    const int kmax = (nb + 3) >> 2;          // uniform within the half
    __half2 z = __float2half2_rn(0.f);
    __half2 h0 = z, h1 = z, h2 = z, h3 = z;  // <= 8 adds before flush
    for (int k = 0; k < kmax; ++k) {
      int i = eg + 4 * k;
      int s = __shfl(idx, (i < nb) ? i : 0, 32);  // width-32, all active
      if (i < nb && fl < RV) {
        uint4 v = *(const uint4*)(mb + ((unsigned)s * RB + fb));
        h0 = __hadd2(h0, *(const __half2*)&v.x);
        h1 = __hadd2(h1, *(const __half2*)&v.y);
        h2 = __hadd2(h2, *(const __half2*)&v.z);
        h3 = __hadd2(h3, *(const __half2*)&v.w);
      }
    }
    float2 f0 = __half22float2(h0), f1 = __half22float2(h1);
    float2 f2 = __half22float2(h2), f3 = __half22float2(h3);
    acc[0] += f0.x; acc[1] += f0.y; acc[2] += f1.x; acc[3] += f1.y;
    acc[4] += f2.x; acc[5] += f2.y; acc[6] += f3.x; acc[7] += f3.y;
  }
  // 2-level reduction over the 4 edge groups (lane bits 3,4 — stays in half)
#pragma unroll
  for (int j = 0; j < 8; ++j) {
    acc[j] += __shfl_xor(acc[j], 8);
    acc[j] += __shfl_xor(acc[j], 16);
  }

  if (eg == 0 && fl < RV) {
    float ni = norm_in[node];
    float4 b0 = ((const float4*)bias)[2 * fl];
    float4 b1 = ((const float4*)bias)[2 * fl + 1];
    float r0[4], r1[4];
    r0[0] = fmaf(acc[0], ni, b0.x); r0[1] = fmaf(acc[1], ni, b0.y);
    r0[2] = fmaf(acc[2], ni, b0.z); r0[3] = fmaf(acc[3], ni, b0.w);
    r1[0] = fmaf(acc[4], ni, b1.x); r1[1] = fmaf(acc[5], ni, b1.y);
    r1[2] = fmaf(acc[6], ni, b1.z); r1[3] = fmaf(acc[7], ni, b1.w);
    if constexpr (RELU) {
      float no = norm_out[node];
#pragma unroll
      for (int j = 0; j < 4; ++j) {
        r0[j] = fmaxf(r0[j], 0.f) * no;
        r1[j] = fmaxf(r1[j], 0.f) * no;
      }
      __half2 p0 = __floats2half2_rn(r0[0], r0[1]);
      __half2 p1 = __floats2half2_rn(r0[2], r0[3]);
      __half2 p2 = __floats2half2_rn(r1[0], r1[1]);
      __half2 p3 = __floats2half2_rn(r1[2], r1[3]);
      uint4 st = {*(unsigned*)&p0, *(unsigned*)&p1,
                  *(unsigned*)&p2, *(unsigned*)&p3};
      ((uint4*)outp)[(size_t)node * RV + fl] = st;   // fp16 h
    } else {
      float* o = (float*)outp + (size_t)node * C + 8 * fl;
      float4 s0 = {r0[0], r0[1], r0[2], r0[3]};
      float4 s1 = {r1[0], r1[1], r1[2], r1[3]};
      *(float4*)o = s0;
      *(float4*)(o + 4) = s1;                        // fp32 final output
    }
  }
}

// ---------------------------------------------------------------------------
extern "C" void kernel_launch(void* const* d_in, const int* in_sizes, int n_in,
                              void* d_out, int out_size, void* d_ws, size_t ws_size,
                              hipStream_t stream) {
  const float* x    = (const float*)d_in[0];
  const float* W0   = (const float*)d_in[1];
  const float* b0   = (const float*)d_in[2];
  const float* W1   = (const float*)d_in[3];
  const float* b1   = (const float*)d_in[4];
  const float* W2   = (const float*)d_in[5];
  const float* b2   = (const float*)d_in[6];
  const int*   esrc = (const int*)d_in[7];
  const int*   edst = (const int*)d_in[8];
  float* out = (float*)d_out;

  // Workspace (4B units): norms/row_ptr/cnt_in/partial + csr_src[NE] +
  // m-region[NN*64 floats] + h-region[NN*64 floats].
  // m, h are fp16 (NN*64 halfs = 12.8 MB each) in the front of their regions.
  // CSR-build transients alias the regions (dead until gemm0):
  //   pin = m-region (NCHUNK*NN ints = 25.6 MB exactly), pout = h-region.
  float*  f        = (float*)d_ws;
  float*  norm_out = f;
  float*  norm_in  = f + NP;
  int*    row_ptr  = (int*)(f + 2 * NP);
  int*    cnt_in   = row_ptr + NP;
  int*    partial  = cnt_in + NP;
  int*    csr_src  = partial + 128;
  float*  mreg     = (float*)(csr_src + NE);
  float*  hreg     = mreg + NN * 64;
  __half* m        = (__half*)mreg;
  __half* h        = (__half*)hreg;
  int*    pin      = (int*)mreg;
  int*    pout     = (int*)hreg;

  // --- CSR build (dst-sorted) + norms: zero global atomics ---
  hist_lds_kernel<<<NSEG * NCHUNK, 1024, 0, stream>>>(edst, pin);
  hist_lds_kernel<<<NSEG * NCHUNK, 1024, 0, stream>>>(esrc, pout);
  merge_kernel<<<(NN + 255) / 256, 256, 0, stream>>>(pin, pout, cnt_in, norm_out, norm_in);
  chunk_sum_kernel<<<NBLK, 256, 0, stream>>>(cnt_in, partial);
  partial_scan_kernel<<<1, 128, 0, stream>>>(partial);
  chunk_scan_kernel<<<NBLK, 256, 0, stream>>>(cnt_in, partial, row_ptr);
  fill_lds_kernel<<<NSEG * NCHUNK, 1024, 0, stream>>>(esrc, edst, row_ptr, pin, csr_src);

  const int gb = (NN + 63) / 64;
  const int gg = (NN + 7) / 8;   // 8 nodes per 256-thread block (2 per wave)

  // Layer 0: m = fp16((x*norm_out) @ W0) ; h = fp16(relu(agg*ni + b0)*no)
  gemm_kernel<128, 64, true, float><<<gb, 256, 0, stream>>>(x, W0, norm_out, m);
  gather_kernel<64, true><<<gg, 256, 0, stream>>>(m, row_ptr, csr_src, norm_in, norm_out, b0, h);

  // Layer 1: m = fp16(h @ W1) ; h = fp16(relu(agg*ni + b1)*no)
  gemm_kernel<64, 64, false, __half><<<gb, 256, 0, stream>>>(h, W1, nullptr, m);
  gather_kernel<64, true><<<gg, 256, 0, stream>>>(m, row_ptr, csr_src, norm_in, norm_out, b1, h);

  // Layer 2: m = fp16(h @ W2) (40 cols) ; out = agg*ni + b2 (fp32)
  gemm_kernel<64, 40, false, __half><<<gb, 256, 0, stream>>>(h, W2, nullptr, m);
  gather_kernel<40, false><<<gg, 256, 0, stream>>>(m, row_ptr, csr_src, norm_in, norm_out, b2, out);
}

// Round 14
// 221.771 us; speedup vs baseline: 1.8078x; 1.0664x over previous
//
#include <hip/hip_runtime.h>
#include <hip/hip_fp16.h>

// GraphConv 3-layer GCN: N=100000 nodes, E=1280000 edges; dims 128->64->64->40.
constexpr int NN = 100000;
constexpr int NE = 1280000;
constexpr int NP = 100352;       // padded N (= 98 * 1024)
constexpr int NBLK = NP / 1024;  // 98 scan chunks

// LDS-segmented histogram geometry.
constexpr int SEGSZ = 16384;                  // 64 KB of int bins per block
constexpr int NSEG = 7;                       // 7*16384 = 114688 >= NN
constexpr int NCHUNK = 64;                    // edge chunks
constexpr int CHSZ = NE / NCHUNK;             // 20000 (exact)

typedef _Float16 half8_t __attribute__((ext_vector_type(8)));
typedef float floatx4 __attribute__((ext_vector_type(4)));

// ---------------------------------------------------------------------------
// Histogram of vals[] into u16 partial[c][n] (stride NN), via LDS bins.
// Per-(chunk,node) count <= CHSZ=20000 < 65536 -> u16 safe (halves traffic).
// ---------------------------------------------------------------------------
__global__ __launch_bounds__(1024) void hist_lds_kernel(
    const int* __restrict__ vals, unsigned short* __restrict__ partial) {
  __shared__ int hcnt[SEGSZ];
  const int s = blockIdx.x % NSEG, c = blockIdx.x / NSEG;
  const int t = threadIdx.x;
#pragma unroll 4
  for (int i = t; i < SEGSZ; i += 1024) hcnt[i] = 0;
  __syncthreads();
  const int lo = s * SEGSZ;
  const int beg = c * CHSZ;
  for (int e = beg + t; e < beg + CHSZ; e += 1024) {
    unsigned v = (unsigned)(vals[e] - lo);
    if (v < (unsigned)SEGSZ) atomicAdd(&hcnt[v], 1);  // LDS atomic
  }
  __syncthreads();
  unsigned short* p = partial + (size_t)c * NN;
#pragma unroll 4
  for (int i = t; i < SEGSZ; i += 1024) {
    int n = lo + i;
    if (n < NN) p[n] = (unsigned short)hcnt[i];
  }
}

// ---------------------------------------------------------------------------
// Merge chunk-partials per node: cnt_in = sum, pin <- exclusive chunk prefix
// (in place, u16; prefix <= in-degree << 65536), norms from degree sums.
// ---------------------------------------------------------------------------
__global__ __launch_bounds__(256) void merge_kernel(
    unsigned short* __restrict__ pin, const unsigned short* __restrict__ pout,
    int* __restrict__ cnt_in, float* __restrict__ norm_out,
    float* __restrict__ norm_in) {
  int n = blockIdx.x * 256 + threadIdx.x;
  if (n >= NN) return;
  int run = 0;
#pragma unroll 8
  for (int c = 0; c < NCHUNK; ++c) {
    size_t idx = (size_t)c * NN + n;
    int v = pin[idx];
    pin[idx] = (unsigned short)run;
    run += v;
  }
  cnt_in[n] = run;
  int s = 0;
#pragma unroll 8
  for (int c = 0; c < NCHUNK; ++c) s += pout[(size_t)c * NN + n];
  norm_in[n]  = rsqrtf(fmaxf((float)run, 1.0f));
  norm_out[n] = rsqrtf(fmaxf((float)s, 1.0f));
}

// ---------------------------------------------------------------------------
// Two-level exclusive scan of cnt_in -> row_ptr
// ---------------------------------------------------------------------------
__global__ __launch_bounds__(256) void chunk_sum_kernel(
    const int* __restrict__ cnt, int* __restrict__ partial) {
  int t = threadIdx.x;
  int base = blockIdx.x * 1024 + t * 4;
  int s = 0;
#pragma unroll
  for (int j = 0; j < 4; ++j) {
    int gi = base + j;
    s += (gi < NN) ? cnt[gi] : 0;
  }
  __shared__ int r[256];
  r[t] = s;
  __syncthreads();
  for (int off = 128; off > 0; off >>= 1) {
    if (t < off) r[t] += r[t + off];
    __syncthreads();
  }
  if (t == 0) partial[blockIdx.x] = r[0];
}

__global__ __launch_bounds__(128) void partial_scan_kernel(int* __restrict__ partial) {
  int t = threadIdx.x;
  int v = (t < NBLK) ? partial[t] : 0;
  __shared__ int s[128];
  s[t] = v;
  __syncthreads();
  for (int off = 1; off < 128; off <<= 1) {
    int add = (t >= off) ? s[t - off] : 0;
    __syncthreads();
    s[t] += add;
    __syncthreads();
  }
  if (t < NBLK) partial[t] = s[t] - v;  // exclusive
}

__global__ __launch_bounds__(256) void chunk_scan_kernel(
    const int* __restrict__ cnt, const int* __restrict__ partial,
    int* __restrict__ row_ptr) {
  int t = threadIdx.x;
  int base = blockIdx.x * 1024 + t * 4;
  int c[4];
#pragma unroll
  for (int j = 0; j < 4; ++j) {
    int gi = base + j;
    c[j] = (gi < NN) ? cnt[gi] : 0;
  }
  int tsum = c[0] + c[1] + c[2] + c[3];
  __shared__ int s[256];
  s[t] = tsum;
  __syncthreads();
  for (int off = 1; off < 256; off <<= 1) {
    int add = (t >= off) ? s[t - off] : 0;
    __syncthreads();
    s[t] += add;
    __syncthreads();
  }
  int run = s[t] - tsum + partial[blockIdx.x];
#pragma unroll
  for (int j = 0; j < 4; ++j) {
    int gi = base + j;
    if (gi <= NN) row_ptr[gi] = run;
    run += c[j];
  }
}

// ---------------------------------------------------------------------------
// CSR fill via LDS cursors (no device atomics).
// ---------------------------------------------------------------------------
__global__ __launch_bounds__(1024) void fill_lds_kernel(
    const int* __restrict__ src, const int* __restrict__ dst,
    const int* __restrict__ row_ptr, const unsigned short* __restrict__ pin,
    int* __restrict__ csr_src) {
  __shared__ int cur[SEGSZ];
  const int s = blockIdx.x % NSEG, c = blockIdx.x / NSEG;
  const int t = threadIdx.x;
  const int lo = s * SEGSZ;
  const unsigned short* base = pin + (size_t)c * NN;
#pragma unroll 4
  for (int i = t; i < SEGSZ; i += 1024) {
    int n = lo + i;
    cur[i] = (n < NN) ? (row_ptr[n] + (int)base[n]) : 0;
  }
  __syncthreads();
  const int beg = c * CHSZ;
  for (int e = beg + t; e < beg + CHSZ; e += 1024) {
    unsigned d = (unsigned)(dst[e] - lo);
    if (d < (unsigned)SEGSZ) {
      int pos = atomicAdd(&cur[d], 1);  // LDS atomic
      csr_src[pos] = src[e];
    }
  }
}

// ---------------------------------------------------------------------------
// Weight prep: W[K][COLS] fp32 -> Wt[col][k] fp16 (transposed), layer 2
// zero-padded to 48 cols. wt layout: wt0[64][128] | wt1[64][64] | wt2[48][64].
// ---------------------------------------------------------------------------
__global__ __launch_bounds__(256) void wprep_kernel(
    const float* __restrict__ W0, const float* __restrict__ W1,
    const float* __restrict__ W2, __half* __restrict__ wt) {
  int t = blockIdx.x * 256 + threadIdx.x;
  if (t < 8192) {                       // wt0: 64 cols x 128 k
    int c = t >> 7, k = t & 127;
    wt[t] = __float2half(W0[k * 64 + c]);
  } else if (t < 12288) {               // wt1: 64 x 64
    int q = t - 8192;
    int c = q >> 6, k = q & 63;
    wt[t] = __float2half(W1[k * 64 + c]);
  } else if (t < 15360) {               // wt2: 48 x 64 (cols >= 40 zero)
    int q = t - 12288;
    int c = q >> 6, k = q & 63;
    wt[t] = __float2half((c < 40) ? W2[k * 40 + c] : 0.0f);
  }
}

// ---------------------------------------------------------------------------
// MFMA GEMM:  m[row,:] = fp16( in[row,:] @ W )  (*norm_out at epilogue if
// SCALE — row scaling commutes past the GEMM).
// Block = 64 rows, wave = 16 rows x COLS. Zero LDS, zero barriers:
//  * A-frag (16x16x32_f16: row=lane&15, k=(lane>>4)*8+j) loaded DIRECTLY
//    from global fp16 rows (16B/lane); fp32 x converted in-reg (layer 0).
//  * B-frag (col=lane&15, same k) from fp16 W^T (tiny, L2-resident).
//  * C/D: col=lane&15, row=(lane>>4)*4+reg  [m89-verified mapping].
// Replaces the VALU GEMM whose 2x ds_read_b128 per 16 FMAs left the LDS
// pipe ~3x oversubscribed (R13 analysis).
// ---------------------------------------------------------------------------
template <int K, int COLS, bool SCALE, typename TIN>
__global__ __launch_bounds__(256) void gemm_mfma_kernel(
    const TIN* __restrict__ in, const __half* __restrict__ wt,
    const float* __restrict__ norm_out, __half* __restrict__ out) {
  constexpr int NT = (COLS + 15) / 16;  // col tiles: 4 (C=64), 3 (C=40 padded)
  const int tid = threadIdx.x;
  const int w = tid >> 6;
  const int l = tid & 63;
  const int lr = l & 15;                // A-row / B-col within tile
  const int kg = l >> 4;                // k-group 0..3
  const int row0 = blockIdx.x * 64 + w * 16;
  const int arow = row0 + lr;

  floatx4 acc[NT];
#pragma unroll
  for (int ct = 0; ct < NT; ++ct) acc[ct] = (floatx4){0.f, 0.f, 0.f, 0.f};

#pragma unroll
  for (int kc = 0; kc < K; kc += 32) {
    half8_t a;
#pragma unroll
    for (int i = 0; i < 8; ++i) a[i] = (_Float16)0.0f;
    if (arow < NN) {
      if constexpr (sizeof(TIN) == 2) {
        a = *(const half8_t*)((const __half*)in + (size_t)arow * K + kc + kg * 8);
      } else {
        const float* p = (const float*)in + (size_t)arow * K + kc + kg * 8;
        float4 f0 = *(const float4*)p;
        float4 f1 = *(const float4*)(p + 4);
        a[0] = (_Float16)f0.x; a[1] = (_Float16)f0.y;
        a[2] = (_Float16)f0.z; a[3] = (_Float16)f0.w;
        a[4] = (_Float16)f1.x; a[5] = (_Float16)f1.y;
        a[6] = (_Float16)f1.z; a[7] = (_Float16)f1.w;
      }
    }
#pragma unroll
    for (int ct = 0; ct < NT; ++ct) {
      half8_t b = *(const half8_t*)((const __half*)wt +
                                    (size_t)(16 * ct + lr) * K + kc + kg * 8);
      acc[ct] = __builtin_amdgcn_mfma_f32_16x16x32_f16(a, b, acc[ct], 0, 0, 0);
    }
  }

#pragma unroll
  for (int ct = 0; ct < NT; ++ct) {
    int col = 16 * ct + lr;
    if (col < COLS) {
#pragma unroll
      for (int r = 0; r < 4; ++r) {
        int grow = row0 + kg * 4 + r;
        if (grow < NN) {
          float v = acc[ct][r];
          if constexpr (SCALE) v *= norm_out[grow];
          out[(size_t)grow * COLS + col] = __float2half(v);
        }
      }
    }
  }
}

// ---------------------------------------------------------------------------
// CSR gather from fp16 m — two nodes per wave (32 lanes each), 4 edge-groups
// x 8 uint4-lanes, width-32 shfl (uniform trip per half — R10 rule), packed
// fp16 inner adds flushed to fp32 per 32-edge batch, 2-level reduction.
// ---------------------------------------------------------------------------
template <int C, bool RELU>
__global__ __launch_bounds__(256) void gather_kernel(
    const __half* __restrict__ m, const int* __restrict__ row_ptr,
    const int* __restrict__ csr_src, const float* __restrict__ norm_in,
    const float* __restrict__ norm_out, const float* __restrict__ bias,
    void* __restrict__ outp) {
  constexpr int RV = C / 8;            // uint4 per row: 8 (C=64), 5 (C=40)
  constexpr unsigned RB = C * 2;       // row bytes: 128 or 80
  const int node = blockIdx.x * 8 + (threadIdx.x >> 5);
  const int l32 = threadIdx.x & 31;    // lane within half-wave
  if (node >= NN) return;
  const int beg = row_ptr[node];
  const int deg = row_ptr[node + 1] - beg;
  const int eg = l32 >> 3;             // edge group 0..3
  const int fl = l32 & 7;              // uint4 index within row
  const char* mb = (const char*)m;
  const unsigned fb = (unsigned)fl * 16u;

  float acc[8] = {};
  for (int base = 0; base < deg; base += 32) {
    const int nb = min(deg - base, 32);
    const int idx = (l32 < nb) ? csr_src[beg + base + l32] : 0;
    const int kmax = (nb + 3) >> 2;          // uniform within the half
    __half2 z = __float2half2_rn(0.f);
    __half2 h0 = z, h1 = z, h2 = z, h3 = z;  // <= 8 adds before flush
    for (int k = 0; k < kmax; ++k) {
      int i = eg + 4 * k;
      int s = __shfl(idx, (i < nb) ? i : 0, 32);  // width-32, all active
      if (i < nb && fl < RV) {
        uint4 v = *(const uint4*)(mb + ((unsigned)s * RB + fb));
        h0 = __hadd2(h0, *(const __half2*)&v.x);
        h1 = __hadd2(h1, *(const __half2*)&v.y);
        h2 = __hadd2(h2, *(const __half2*)&v.z);
        h3 = __hadd2(h3, *(const __half2*)&v.w);
      }
    }
    float2 f0 = __half22float2(h0), f1 = __half22float2(h1);
    float2 f2 = __half22float2(h2), f3 = __half22float2(h3);
    acc[0] += f0.x; acc[1] += f0.y; acc[2] += f1.x; acc[3] += f1.y;
    acc[4] += f2.x; acc[5] += f2.y; acc[6] += f3.x; acc[7] += f3.y;
  }
#pragma unroll
  for (int j = 0; j < 8; ++j) {
    acc[j] += __shfl_xor(acc[j], 8);
    acc[j] += __shfl_xor(acc[j], 16);
  }

  if (eg == 0 && fl < RV) {
    float ni = norm_in[node];
    float4 b0 = ((const float4*)bias)[2 * fl];
    float4 b1 = ((const float4*)bias)[2 * fl + 1];
    float r0[4], r1[4];
    r0[0] = fmaf(acc[0], ni, b0.x); r0[1] = fmaf(acc[1], ni, b0.y);
    r0[2] = fmaf(acc[2], ni, b0.z); r0[3] = fmaf(acc[3], ni, b0.w);
    r1[0] = fmaf(acc[4], ni, b1.x); r1[1] = fmaf(acc[5], ni, b1.y);
    r1[2] = fmaf(acc[6], ni, b1.z); r1[3] = fmaf(acc[7], ni, b1.w);
    if constexpr (RELU) {
      float no = norm_out[node];
#pragma unroll
      for (int j = 0; j < 4; ++j) {
        r0[j] = fmaxf(r0[j], 0.f) * no;
        r1[j] = fmaxf(r1[j], 0.f) * no;
      }
      __half2 p0 = __floats2half2_rn(r0[0], r0[1]);
      __half2 p1 = __floats2half2_rn(r0[2], r0[3]);
      __half2 p2 = __floats2half2_rn(r1[0], r1[1]);
      __half2 p3 = __floats2half2_rn(r1[2], r1[3]);
      uint4 st = {*(unsigned*)&p0, *(unsigned*)&p1,
                  *(unsigned*)&p2, *(unsigned*)&p3};
      ((uint4*)outp)[(size_t)node * RV + fl] = st;   // fp16 h
    } else {
      float* o = (float*)outp + (size_t)node * C + 8 * fl;
      float4 s0 = {r0[0], r0[1], r0[2], r0[3]};
      float4 s1 = {r1[0], r1[1], r1[2], r1[3]};
      *(float4*)o = s0;
      *(float4*)(o + 4) = s1;                        // fp32 final output
    }
  }
}

// ---------------------------------------------------------------------------
extern "C" void kernel_launch(void* const* d_in, const int* in_sizes, int n_in,
                              void* d_out, int out_size, void* d_ws, size_t ws_size,
                              hipStream_t stream) {
  const float* x    = (const float*)d_in[0];
  const float* W0   = (const float*)d_in[1];
  const float* b0   = (const float*)d_in[2];
  const float* W1   = (const float*)d_in[3];
  const float* b1   = (const float*)d_in[4];
  const float* W2   = (const float*)d_in[5];
  const float* b2   = (const float*)d_in[6];
  const int*   esrc = (const int*)d_in[7];
  const int*   edst = (const int*)d_in[8];
  float* out = (float*)d_out;

  // Workspace (4B units): norms/row_ptr/cnt_in/partial + csr_src[NE] +
  // m-region[NN*64 floats] + h-region[NN*64 floats].
  // m, h fp16 occupy the FRONT half (12.8 MB) of their regions.
  // Aliases (stream-ordered, no overlap in time or space):
  //   pin  = u16 NCHUNK*NN (12.8 MB) in m-region front (dead before gemm0)
  //   pout = u16 NCHUNK*NN in h-region front (dead after merge)
  //   wt   = fp16 15360 in h-region BACK half (written by wprep, read by gemms)
  float*  f        = (float*)d_ws;
  float*  norm_out = f;
  float*  norm_in  = f + NP;
  int*    row_ptr  = (int*)(f + 2 * NP);
  int*    cnt_in   = row_ptr + NP;
  int*    partial  = cnt_in + NP;
  int*    csr_src  = partial + 128;
  float*  mreg     = (float*)(csr_src + NE);
  float*  hreg     = mreg + NN * 64;
  __half* m        = (__half*)mreg;
  __half* h        = (__half*)hreg;
  unsigned short* pin  = (unsigned short*)mreg;
  unsigned short* pout = (unsigned short*)hreg;
  __half* wt       = (__half*)hreg + (size_t)NN * 64;  // back half of h-region

  // --- W transpose+fp16 prep (independent; needed by gemm0) ---
  wprep_kernel<<<60, 256, 0, stream>>>(W0, W1, W2, wt);

  // --- CSR build (dst-sorted) + norms: zero global atomics, u16 partials ---
  hist_lds_kernel<<<NSEG * NCHUNK, 1024, 0, stream>>>(edst, pin);
  hist_lds_kernel<<<NSEG * NCHUNK, 1024, 0, stream>>>(esrc, pout);
  merge_kernel<<<(NN + 255) / 256, 256, 0, stream>>>(pin, pout, cnt_in, norm_out, norm_in);
  chunk_sum_kernel<<<NBLK, 256, 0, stream>>>(cnt_in, partial);
  partial_scan_kernel<<<1, 128, 0, stream>>>(partial);
  chunk_scan_kernel<<<NBLK, 256, 0, stream>>>(cnt_in, partial, row_ptr);
  fill_lds_kernel<<<NSEG * NCHUNK, 1024, 0, stream>>>(esrc, edst, row_ptr, pin, csr_src);

  const int gb = (NN + 63) / 64;
  const int gg = (NN + 7) / 8;   // 8 nodes per 256-thread block (2 per wave)

  // Layer 0: m = fp16((x @ W0) * norm_out) ; h = fp16(relu(agg*ni + b0)*no)
  gemm_mfma_kernel<128, 64, true, float><<<gb, 256, 0, stream>>>(x, wt, norm_out, m);
  gather_kernel<64, true><<<gg, 256, 0, stream>>>(m, row_ptr, csr_src, norm_in, norm_out, b0, h);

  // Layer 1: m = fp16(h @ W1) ; h = fp16(relu(agg*ni + b1)*no)
  gemm_mfma_kernel<64, 64, false, __half><<<gb, 256, 0, stream>>>(h, wt + 8192, nullptr, m);
  gather_kernel<64, true><<<gg, 256, 0, stream>>>(m, row_ptr, csr_src, norm_in, norm_out, b1, h);

  // Layer 2: m = fp16(h @ W2) (40 cols) ; out = agg*ni + b2 (fp32)
  gemm_mfma_kernel<64, 40, false, __half><<<gb, 256, 0, stream>>>(h, wt + 12288, nullptr, m);
  gather_kernel<40, false><<<gg, 256, 0, stream>>>(m, row_ptr, csr_src, norm_in, norm_out, b2, out);
}

// Round 15
// 202.235 us; speedup vs baseline: 1.9825x; 1.0966x over previous
//
#include <hip/hip_runtime.h>
#include <hip/hip_fp16.h>

// GraphConv 3-layer GCN: N=100000 nodes, E=1280000 edges; dims 128->64->64->40.
constexpr int NN = 100000;
constexpr int NE = 1280000;
constexpr int NP = 100352;       // padded N (= 98 * 1024)
constexpr int NBLK = NP / 1024;  // 98 scan chunks

constexpr int NCHUNK = 64;       // edge chunks
constexpr int CHSZ = NE / NCHUNK;  // 20000 (exact)

// Combined-histogram geometry: u16-packed LDS bins, 2 arrays (dst+src),
// 128 KB LDS/block (gfx950 allows 160 KB/workgroup).
constexpr int HSEG = 32768;      // nodes per segment
constexpr int NHSEG = 4;         // 4*32768 = 131072 >= NN

// Fill geometry: int LDS cursors, 64 KB.
constexpr int SEGSZ = 16384;
constexpr int NSEG = 7;          // 7*16384 = 114688 >= NN

typedef _Float16 half8_t __attribute__((ext_vector_type(8)));
typedef float floatx4 __attribute__((ext_vector_type(4)));

// ---------------------------------------------------------------------------
// Combined histogram: ONE pass over each edge chunk counts BOTH dst (pin)
// and src (pout) into u16-packed LDS bins. Per-(chunk,node) count <= 20000
// < 65536 -> no carry across packed halves. Replaces two 7-pass kernels
// (71.7 MB edge reads) with one 4-pass kernel (41 MB).
// ---------------------------------------------------------------------------
__global__ __launch_bounds__(1024) void hist2_kernel(
    const int* __restrict__ dst, const int* __restrict__ src,
    unsigned short* __restrict__ pin, unsigned short* __restrict__ pout) {
  __shared__ unsigned bin_in[HSEG / 2];   // 64 KB
  __shared__ unsigned bin_out[HSEG / 2];  // 64 KB
  const int s = blockIdx.x % NHSEG, c = blockIdx.x / NHSEG;
  const int t = threadIdx.x;
#pragma unroll 4
  for (int i = t; i < HSEG / 2; i += 1024) { bin_in[i] = 0; bin_out[i] = 0; }
  __syncthreads();
  const int lo = s * HSEG;
  const int beg = c * CHSZ;
  for (int e = beg + t; e < beg + CHSZ; e += 1024) {
    unsigned d = (unsigned)(dst[e] - lo);
    unsigned v = (unsigned)(src[e] - lo);
    if (d < (unsigned)HSEG) atomicAdd(&bin_in[d >> 1], 1u << ((d & 1) * 16));
    if (v < (unsigned)HSEG) atomicAdd(&bin_out[v >> 1], 1u << ((v & 1) * 16));
  }
  __syncthreads();
  // Dump as u32 words (nodes 2i, 2i+1); NN and c*NN even -> aligned.
  unsigned* pi = (unsigned*)(pin + (size_t)c * NN);
  unsigned* po = (unsigned*)(pout + (size_t)c * NN);
#pragma unroll 4
  for (int i = t; i < HSEG / 2; i += 1024) {
    int w = (lo >> 1) + i;
    if (2 * w < NN) { pi[w] = bin_in[i]; po[w] = bin_out[i]; }
  }
}

// ---------------------------------------------------------------------------
// Merge chunk-partials per node: cnt_in = sum, pin <- exclusive chunk prefix
// (in place, u16; prefix <= in-degree << 65536), norms from degree sums.
// ---------------------------------------------------------------------------
__global__ __launch_bounds__(256) void merge_kernel(
    unsigned short* __restrict__ pin, const unsigned short* __restrict__ pout,
    int* __restrict__ cnt_in, float* __restrict__ norm_out,
    float* __restrict__ norm_in) {
  int n = blockIdx.x * 256 + threadIdx.x;
  if (n >= NN) return;
  int run = 0;
#pragma unroll 8
  for (int c = 0; c < NCHUNK; ++c) {
    size_t idx = (size_t)c * NN + n;
    int v = pin[idx];
    pin[idx] = (unsigned short)run;
    run += v;
  }
  cnt_in[n] = run;
  int s = 0;
#pragma unroll 8
  for (int c = 0; c < NCHUNK; ++c) s += pout[(size_t)c * NN + n];
  norm_in[n]  = rsqrtf(fmaxf((float)run, 1.0f));
  norm_out[n] = rsqrtf(fmaxf((float)s, 1.0f));
}

// ---------------------------------------------------------------------------
// Two-level exclusive scan of cnt_in -> row_ptr
// ---------------------------------------------------------------------------
__global__ __launch_bounds__(256) void chunk_sum_kernel(
    const int* __restrict__ cnt, int* __restrict__ partial) {
  int t = threadIdx.x;
  int base = blockIdx.x * 1024 + t * 4;
  int s = 0;
#pragma unroll
  for (int j = 0; j < 4; ++j) {
    int gi = base + j;
    s += (gi < NN) ? cnt[gi] : 0;
  }
  __shared__ int r[256];
  r[t] = s;
  __syncthreads();
  for (int off = 128; off > 0; off >>= 1) {
    if (t < off) r[t] += r[t + off];
    __syncthreads();
  }
  if (t == 0) partial[blockIdx.x] = r[0];
}

__global__ __launch_bounds__(128) void partial_scan_kernel(int* __restrict__ partial) {
  int t = threadIdx.x;
  int v = (t < NBLK) ? partial[t] : 0;
  __shared__ int s[128];
  s[t] = v;
  __syncthreads();
  for (int off = 1; off < 128; off <<= 1) {
    int add = (t >= off) ? s[t - off] : 0;
    __syncthreads();
    s[t] += add;
    __syncthreads();
  }
  if (t < NBLK) partial[t] = s[t] - v;  // exclusive
}

__global__ __launch_bounds__(256) void chunk_scan_kernel(
    const int* __restrict__ cnt, const int* __restrict__ partial,
    int* __restrict__ row_ptr) {
  int t = threadIdx.x;
  int base = blockIdx.x * 1024 + t * 4;
  int c[4];
#pragma unroll
  for (int j = 0; j < 4; ++j) {
    int gi = base + j;
    c[j] = (gi < NN) ? cnt[gi] : 0;
  }
  int tsum = c[0] + c[1] + c[2] + c[3];
  __shared__ int s[256];
  s[t] = tsum;
  __syncthreads();
  for (int off = 1; off < 256; off <<= 1) {
    int add = (t >= off) ? s[t - off] : 0;
    __syncthreads();
    s[t] += add;
    __syncthreads();
  }
  int run = s[t] - tsum + partial[blockIdx.x];
#pragma unroll
  for (int j = 0; j < 4; ++j) {
    int gi = base + j;
    if (gi <= NN) row_ptr[gi] = run;
    run += c[j];
  }
}

// ---------------------------------------------------------------------------
// CSR fill via LDS cursors (no device atomics).
// ---------------------------------------------------------------------------
__global__ __launch_bounds__(1024) void fill_lds_kernel(
    const int* __restrict__ src, const int* __restrict__ dst,
    const int* __restrict__ row_ptr, const unsigned short* __restrict__ pin,
    int* __restrict__ csr_src) {
  __shared__ int cur[SEGSZ];
  const int s = blockIdx.x % NSEG, c = blockIdx.x / NSEG;
  const int t = threadIdx.x;
  const int lo = s * SEGSZ;
  const unsigned short* base = pin + (size_t)c * NN;
#pragma unroll 4
  for (int i = t; i < SEGSZ; i += 1024) {
    int n = lo + i;
    cur[i] = (n < NN) ? (row_ptr[n] + (int)base[n]) : 0;
  }
  __syncthreads();
  const int beg = c * CHSZ;
  for (int e = beg + t; e < beg + CHSZ; e += 1024) {
    unsigned d = (unsigned)(dst[e] - lo);
    if (d < (unsigned)SEGSZ) {
      int pos = atomicAdd(&cur[d], 1);  // LDS atomic
      csr_src[pos] = src[e];
    }
  }
}

// ---------------------------------------------------------------------------
// Weight prep: W[K][COLS] fp32 -> Wt[col][k] fp16 (transposed), layer 2
// zero-padded to 48 cols. wt layout: wt0[64][128] | wt1[64][64] | wt2[48][64].
// ---------------------------------------------------------------------------
__global__ __launch_bounds__(256) void wprep_kernel(
    const float* __restrict__ W0, const float* __restrict__ W1,
    const float* __restrict__ W2, __half* __restrict__ wt) {
  int t = blockIdx.x * 256 + threadIdx.x;
  if (t < 8192) {                       // wt0: 64 cols x 128 k
    int c = t >> 7, k = t & 127;
    wt[t] = __float2half(W0[k * 64 + c]);
  } else if (t < 12288) {               // wt1: 64 x 64
    int q = t - 8192;
    int c = q >> 6, k = q & 63;
    wt[t] = __float2half(W1[k * 64 + c]);
  } else if (t < 15360) {               // wt2: 48 x 64 (cols >= 40 zero)
    int q = t - 12288;
    int c = q >> 6, k = q & 63;
    wt[t] = __float2half((c < 40) ? W2[k * 40 + c] : 0.0f);
  }
}

// ---------------------------------------------------------------------------
// MFMA GEMM:  m[row,:] = fp16( in[row,:] @ W )  (*norm_out if SCALE).
// Block = 64 rows, wave = 16 rows x COLS; zero LDS, zero barriers.
// A-frag direct from global rows; B-frag from fp16 W^T (L2-resident).
// C/D: col=lane&15, row=(lane>>4)*4+reg  [m89-verified mapping].
// ---------------------------------------------------------------------------
template <int K, int COLS, bool SCALE, typename TIN>
__global__ __launch_bounds__(256) void gemm_mfma_kernel(
    const TIN* __restrict__ in, const __half* __restrict__ wt,
    const float* __restrict__ norm_out, __half* __restrict__ out) {
  constexpr int NT = (COLS + 15) / 16;  // col tiles: 4 (C=64), 3 (C=40 padded)
  const int tid = threadIdx.x;
  const int w = tid >> 6;
  const int l = tid & 63;
  const int lr = l & 15;                // A-row / B-col within tile
  const int kg = l >> 4;                // k-group 0..3
  const int row0 = blockIdx.x * 64 + w * 16;
  const int arow = row0 + lr;

  floatx4 acc[NT];
#pragma unroll
  for (int ct = 0; ct < NT; ++ct) acc[ct] = (floatx4){0.f, 0.f, 0.f, 0.f};

#pragma unroll
  for (int kc = 0; kc < K; kc += 32) {
    half8_t a;
#pragma unroll
    for (int i = 0; i < 8; ++i) a[i] = (_Float16)0.0f;
    if (arow < NN) {
      if constexpr (sizeof(TIN) == 2) {
        a = *(const half8_t*)((const __half*)in + (size_t)arow * K + kc + kg * 8);
      } else {
        const float* p = (const float*)in + (size_t)arow * K + kc + kg * 8;
        float4 f0 = *(const float4*)p;
        float4 f1 = *(const float4*)(p + 4);
        a[0] = (_Float16)f0.x; a[1] = (_Float16)f0.y;
        a[2] = (_Float16)f0.z; a[3] = (_Float16)f0.w;
        a[4] = (_Float16)f1.x; a[5] = (_Float16)f1.y;
        a[6] = (_Float16)f1.z; a[7] = (_Float16)f1.w;
      }
    }
#pragma unroll
    for (int ct = 0; ct < NT; ++ct) {
      half8_t b = *(const half8_t*)((const __half*)wt +
                                    (size_t)(16 * ct + lr) * K + kc + kg * 8);
      acc[ct] = __builtin_amdgcn_mfma_f32_16x16x32_f16(a, b, acc[ct], 0, 0, 0);
    }
  }

#pragma unroll
  for (int ct = 0; ct < NT; ++ct) {
    int col = 16 * ct + lr;
    if (col < COLS) {
#pragma unroll
      for (int r = 0; r < 4; ++r) {
        int grow = row0 + kg * 4 + r;
        if (grow < NN) {
          float v = acc[ct][r];
          if constexpr (SCALE) v *= norm_out[grow];
          out[(size_t)grow * COLS + col] = __float2half(v);
        }
      }
    }
  }
}

// ---------------------------------------------------------------------------
// CSR gather from fp16 m — two nodes per wave, 4 edge-groups x 8 uint4-lanes,
// width-32 shfl (uniform trip per half — R10 rule). Inner k-loop UNROLLED x2:
// two independent row-loads in flight per iteration (zero-padded past nb —
// fp16 +0 is exact), doubling MLP in the latency-bound loop.
// ---------------------------------------------------------------------------
template <int C, bool RELU>
__global__ __launch_bounds__(256) void gather_kernel(
    const __half* __restrict__ m, const int* __restrict__ row_ptr,
    const int* __restrict__ csr_src, const float* __restrict__ norm_in,
    const float* __restrict__ norm_out, const float* __restrict__ bias,
    void* __restrict__ outp) {
  constexpr int RV = C / 8;            // uint4 per row: 8 (C=64), 5 (C=40)
  constexpr unsigned RB = C * 2;       // row bytes: 128 or 80
  const int node = blockIdx.x * 8 + (threadIdx.x >> 5);
  const int l32 = threadIdx.x & 31;    // lane within half-wave
  if (node >= NN) return;
  const int beg = row_ptr[node];
  const int deg = row_ptr[node + 1] - beg;
  const int eg = l32 >> 3;             // edge group 0..3
  const int fl = l32 & 7;              // uint4 index within row
  const bool flok = (RV == 8) ? true : (fl < RV);
  const char* mb = (const char*)m;
  const unsigned fb = (unsigned)fl * 16u;

  float acc[8] = {};
  for (int base = 0; base < deg; base += 32) {
    const int nb = min(deg - base, 32);
    const int idx = (l32 < nb) ? csr_src[beg + base + l32] : 0;
    const int kmax = (nb + 3) >> 2;          // uniform within the half
    __half2 z = __float2half2_rn(0.f);
    __half2 h0 = z, h1 = z, h2 = z, h3 = z;  // <= 8 adds/acc before flush
    for (int k = 0; k < kmax; k += 2) {
      int i0 = eg + 4 * k;
      int i1 = i0 + 4;
      int s0 = __shfl(idx, (i0 < nb) ? i0 : 0, 32);  // all lanes active
      int s1 = __shfl(idx, (i1 < nb) ? i1 : 0, 32);
      uint4 v0 = {0u, 0u, 0u, 0u}, v1 = {0u, 0u, 0u, 0u};
      if (i0 < nb && flok) v0 = *(const uint4*)(mb + ((unsigned)s0 * RB + fb));
      if (k + 1 < kmax && i1 < nb && flok)
        v1 = *(const uint4*)(mb + ((unsigned)s1 * RB + fb));
      h0 = __hadd2(__hadd2(h0, *(const __half2*)&v0.x), *(const __half2*)&v1.x);
      h1 = __hadd2(__hadd2(h1, *(const __half2*)&v0.y), *(const __half2*)&v1.y);
      h2 = __hadd2(__hadd2(h2, *(const __half2*)&v0.z), *(const __half2*)&v1.z);
      h3 = __hadd2(__hadd2(h3, *(const __half2*)&v0.w), *(const __half2*)&v1.w);
    }
    float2 f0 = __half22float2(h0), f1 = __half22float2(h1);
    float2 f2 = __half22float2(h2), f3 = __half22float2(h3);
    acc[0] += f0.x; acc[1] += f0.y; acc[2] += f1.x; acc[3] += f1.y;
    acc[4] += f2.x; acc[5] += f2.y; acc[6] += f3.x; acc[7] += f3.y;
  }
#pragma unroll
  for (int j = 0; j < 8; ++j) {
    acc[j] += __shfl_xor(acc[j], 8);
    acc[j] += __shfl_xor(acc[j], 16);
  }

  if (eg == 0 && flok) {
    float ni = norm_in[node];
    float4 b0 = ((const float4*)bias)[2 * fl];
    float4 b1 = ((const float4*)bias)[2 * fl + 1];
    float r0[4], r1[4];
    r0[0] = fmaf(acc[0], ni, b0.x); r0[1] = fmaf(acc[1], ni, b0.y);
    r0[2] = fmaf(acc[2], ni, b0.z); r0[3] = fmaf(acc[3], ni, b0.w);
    r1[0] = fmaf(acc[4], ni, b1.x); r1[1] = fmaf(acc[5], ni, b1.y);
    r1[2] = fmaf(acc[6], ni, b1.z); r1[3] = fmaf(acc[7], ni, b1.w);
    if constexpr (RELU) {
      float no = norm_out[node];
#pragma unroll
      for (int j = 0; j < 4; ++j) {
        r0[j] = fmaxf(r0[j], 0.f) * no;
        r1[j] = fmaxf(r1[j], 0.f) * no;
      }
      __half2 p0 = __floats2half2_rn(r0[0], r0[1]);
      __half2 p1 = __floats2half2_rn(r0[2], r0[3]);
      __half2 p2 = __floats2half2_rn(r1[0], r1[1]);
      __half2 p3 = __floats2half2_rn(r1[2], r1[3]);
      uint4 st = {*(unsigned*)&p0, *(unsigned*)&p1,
                  *(unsigned*)&p2, *(unsigned*)&p3};
      ((uint4*)outp)[(size_t)node * RV + fl] = st;   // fp16 h
    } else {
      float* o = (float*)outp + (size_t)node * C + 8 * fl;
      float4 s0 = {r0[0], r0[1], r0[2], r0[3]};
      float4 s1 = {r1[0], r1[1], r1[2], r1[3]};
      *(float4*)o = s0;
      *(float4*)(o + 4) = s1;                        // fp32 final output
    }
  }
}

// ---------------------------------------------------------------------------
extern "C" void kernel_launch(void* const* d_in, const int* in_sizes, int n_in,
                              void* d_out, int out_size, void* d_ws, size_t ws_size,
                              hipStream_t stream) {
  const float* x    = (const float*)d_in[0];
  const float* W0   = (const float*)d_in[1];
  const float* b0   = (const float*)d_in[2];
  const float* W1   = (const float*)d_in[3];
  const float* b1   = (const float*)d_in[4];
  const float* W2   = (const float*)d_in[5];
  const float* b2   = (const float*)d_in[6];
  const int*   esrc = (const int*)d_in[7];
  const int*   edst = (const int*)d_in[8];
  float* out = (float*)d_out;

  // Workspace (4B units): norms/row_ptr/cnt_in/partial + csr_src[NE] +
  // m-region[NN*64 floats] + h-region[NN*64 floats].
  // m, h fp16 occupy the FRONT half (12.8 MB) of their regions.
  // Aliases (stream-ordered, no overlap in time or space):
  //   pin  = u16 NCHUNK*NN (12.8 MB) in m-region front (dead before gemm0)
  //   pout = u16 NCHUNK*NN in h-region front (dead after merge)
  //   wt   = fp16 15360 in h-region BACK half (written by wprep, read by gemms)
  float*  f        = (float*)d_ws;
  float*  norm_out = f;
  float*  norm_in  = f + NP;
  int*    row_ptr  = (int*)(f + 2 * NP);
  int*    cnt_in   = row_ptr + NP;
  int*    partial  = cnt_in + NP;
  int*    csr_src  = partial + 128;
  float*  mreg     = (float*)(csr_src + NE);
  float*  hreg     = mreg + NN * 64;
  __half* m        = (__half*)mreg;
  __half* h        = (__half*)hreg;
  unsigned short* pin  = (unsigned short*)mreg;
  unsigned short* pout = (unsigned short*)hreg;
  __half* wt       = (__half*)hreg + (size_t)NN * 64;  // back half of h-region

  // --- W transpose+fp16 prep (independent; needed by gemm0) ---
  wprep_kernel<<<60, 256, 0, stream>>>(W0, W1, W2, wt);

  // --- CSR build (dst-sorted) + norms: zero global atomics, u16 partials ---
  hist2_kernel<<<NHSEG * NCHUNK, 1024, 0, stream>>>(edst, esrc, pin, pout);
  merge_kernel<<<(NN + 255) / 256, 256, 0, stream>>>(pin, pout, cnt_in, norm_out, norm_in);
  chunk_sum_kernel<<<NBLK, 256, 0, stream>>>(cnt_in, partial);
  partial_scan_kernel<<<1, 128, 0, stream>>>(partial);
  chunk_scan_kernel<<<NBLK, 256, 0, stream>>>(cnt_in, partial, row_ptr);
  fill_lds_kernel<<<NSEG * NCHUNK, 1024, 0, stream>>>(esrc, edst, row_ptr, pin, csr_src);

  const int gb = (NN + 63) / 64;
  const int gg = (NN + 7) / 8;   // 8 nodes per 256-thread block (2 per wave)

  // Layer 0: m = fp16((x @ W0) * norm_out) ; h = fp16(relu(agg*ni + b0)*no)
  gemm_mfma_kernel<128, 64, true, float><<<gb, 256, 0, stream>>>(x, wt, norm_out, m);
  gather_kernel<64, true><<<gg, 256, 0, stream>>>(m, row_ptr, csr_src, norm_in, norm_out, b0, h);

  // Layer 1: m = fp16(h @ W1) ; h = fp16(relu(agg*ni + b1)*no)
  gemm_mfma_kernel<64, 64, false, __half><<<gb, 256, 0, stream>>>(h, wt + 8192, nullptr, m);
  gather_kernel<64, true><<<gg, 256, 0, stream>>>(m, row_ptr, csr_src, norm_in, norm_out, b1, h);

  // Layer 2: m = fp16(h @ W2) (40 cols) ; out = agg*ni + b2 (fp32)
  gemm_mfma_kernel<64, 40, false, __half><<<gb, 256, 0, stream>>>(h, wt + 12288, nullptr, m);
  gather_kernel<40, false><<<gg, 256, 0, stream>>>(m, row_ptr, csr_src, norm_in, norm_out, b2, out);
}